// Round 14
// baseline (1182.467 us; speedup 1.0000x reference)
//
#include <hip/hip_runtime.h>
#include <math.h>

#define D       256
#define NROWS   32768      // 8 * 4096
#define CODES   8192
#define QOFF    8388608    // index output offset (floats) in d_out

// ---------------- coarse GEMM config ----------------
#define BM      256
#define BN      256
#define NSPL    2
#define SPLC    (CODES / NSPL)    // 4096
#define NCHUNK  (SPLC / BN)       // 16
#define NSTEP   (NCHUNK * 4)      // 64 kb-steps (BK=64)
#define NBLK    256               // 128 rowTiles * NSPL
#define LQ      2048              // LDS candidate buffer entries (per chunk)
#define SEGQ    12288u            // per-block candidate segment entries (8B)
#define OVCAP   262144u
#define CAP2    1048576u

// rigorous collect margin (2M): 2*2*(2u+u^2)*||x||max*||e||max, u=2^-9 (bf16 rn)
#define MARG_COEF 0.016f
#define MARG_ABS  0.10f

// ---------------- ws layout (bytes) ----------------
#define OFF_AH    0ull               // 16,777,216
#define OFF_X2    16777216ull
#define OFF_NX    16908288ull
#define OFF_E2    17039360ull
#define OFF_RM    17072128ull        // monotone-encoded float bits
#define OFF_PK    17203200ull
#define OFF_MISC  17465344ull        // [1]=ovCnt [2]=neMaxBits [3]=survCnt [4]=nxMaxBits
#define OFF_BCNT  17465600ull
#define OFF_L2    17469696ull        // CAP2 * 4
#define OFF_CAND  21664000ull        // uint2: NBLK*SEGQ segs + OVCAP overflow
#define WS_NEED   48926976ull        // < 51,019,776 proven in round 2

typedef __attribute__((ext_vector_type(8)))  short bf16x8;
typedef __attribute__((ext_vector_type(16))) float f32x16;

__device__ __forceinline__ void gload16(const void* g, void* l) {
  __builtin_amdgcn_global_load_lds(
      (const __attribute__((address_space(1))) unsigned int*)g,
      (__attribute__((address_space(3))) unsigned int*)l, 16, 0, 0);
}

__device__ __forceinline__ unsigned short bf16rn(float x) {
  unsigned u = __float_as_uint(x);
  return (unsigned short)((u + 0x7fffu + ((u >> 16) & 1u)) >> 16);
}

// monotone float <-> uint (order-preserving incl. negatives)
__device__ __forceinline__ unsigned encf(float f) {
  unsigned b = __float_as_uint(f);
  return (b >> 31) ? ~b : (b | 0x80000000u);
}
__device__ __forceinline__ float decf(unsigned u) {
  return __uint_as_float((u >> 31) ? (u ^ 0x80000000u) : ~u);
}

// ---------------------------------------------------------------------------
__global__ __launch_bounds__(256) void init_kernel(unsigned* __restrict__ misc,
                                                   unsigned* __restrict__ rowMinU,
                                                   unsigned long long* __restrict__ pKey) {
  int i = blockIdx.x * 256 + threadIdx.x;   // 32768
  if (i < 16) misc[i] = 0u;
  rowMinU[i] = 0xFFFFFFFFu;
  pKey[i] = ~0ull;
}

// ---------------------------------------------------------------------------
// prep: bf16 h-planes + squared norms + neMax + nxMax.
// ---------------------------------------------------------------------------
__global__ __launch_bounds__(256) void prep_kernel(const float* __restrict__ x,
                                                   const float* __restrict__ embed,
                                                   unsigned short* __restrict__ A_h,
                                                   unsigned short* __restrict__ E_h,
                                                   float* __restrict__ x2,
                                                   float* __restrict__ nx,
                                                   float* __restrict__ e2,
                                                   unsigned* __restrict__ misc) {
  int wid  = threadIdx.x >> 6;
  int lane = threadIdx.x & 63;
  int rid  = blockIdx.x * 4 + wid;   // 0..40959
  const float* src;
  unsigned short* dst;
  if (rid < NROWS) { src = x + (size_t)rid * D;               dst = A_h + (size_t)rid * D; }
  else             { src = embed + (size_t)(rid - NROWS) * D; dst = E_h + (size_t)(rid - NROWS) * D; }
  float4 v = *(const float4*)(src + lane * 4);
  ushort4 hv = make_ushort4(bf16rn(v.x), bf16rn(v.y), bf16rn(v.z), bf16rn(v.w));
  *(ushort4*)(dst + lane * 4) = hv;
  float p = v.x * v.x + v.y * v.y + v.z * v.z + v.w * v.w;
  #pragma unroll
  for (int off = 32; off > 0; off >>= 1) p += __shfl_down(p, off);
  if (lane == 0) {
    float n = sqrtf(p);
    if (rid < NROWS) { x2[rid] = p; nx[rid] = n; atomicMax(&misc[4], __float_as_uint(n)); }
    else { e2[rid - NROWS] = p; atomicMax(&misc[2], __float_as_uint(n)); }
  }
}

// ---------------------------------------------------------------------------
// Fused coarse pass (round-9 engine, register-engineered <=128 arch VGPR):
// 256x256 tile, 8 waves (4x2), wave 64x128 = 2x4 frags of 32x32x16, 2-phase
// dbuf.  Per chunk: in-place q transform (acc = e2-2*xe) + running row-min
// (+ butterfly over the 32 col-lanes) then collect acc <= runm + rc (GLOBAL
// scalar margin) into LDS, flushed per chunk to a private per-block segment.
// Superset proof: runm_t >= rowMin_final, so any q <= rowMin_final + rc is
// collected; the filter then reduces to the proven survivor set.
// ---------------------------------------------------------------------------
__global__ __launch_bounds__(512, 2) void gemm_coarse(
    const unsigned short* __restrict__ A_h,
    const unsigned short* __restrict__ E_h,
    const float* __restrict__ e2g,
    const unsigned* __restrict__ miscR,
    unsigned* __restrict__ rowMinU,
    uint2* __restrict__ cand,           // NBLK*SEGQ segments + OVCAP tail
    unsigned* __restrict__ blkCnt,
    unsigned* __restrict__ ovCnt) {     // &misc[1]
  __shared__ __align__(16) char As0[32768];   // 256 rows x 128B (BK=64)
  __shared__ __align__(16) char As1[32768];
  __shared__ __align__(16) char Bs0[32768];
  __shared__ __align__(16) char Bs1[32768];
  __shared__ uint2 lbuf[LQ];                  // 16KB
  __shared__ unsigned lcnt, lnS, lbaseS;

  const int tid  = threadIdx.x;
  const int lane = tid & 63;
  const int wave = tid >> 6;            // 0..7
  const int wm = wave >> 1;             // 0..3  row group (64 rows)
  const int wn = wave & 1;              // 0..1  col group (128 cols)
  const int l31 = lane & 31;
  const int hi16 = (lane >> 5) << 4;
  const int lh4  = (lane >> 5) << 2;
  const int rowBase = blockIdx.x * BM;
  const int split   = blockIdx.y;
  const int seg     = blockIdx.y * 128 + blockIdx.x;

  // per-lane read geometry: row&7 == l31&7 for both A and B fragment rows.
  const int Ccom = hi16 ^ ((l31 & 7) << 4);
  const int Aoff = (wm * 64 + l31) << 7;    // + f*4096 + (Ccom^ks*32)
  const int Boff = (wn * 128 + l31) << 7;   // + g*4096 + (Ccom^ks*32)

  // staging addressing, algebraically reduced to 3 registers:
  //   q = i*512+tid; u = SWK(q<<4)  ==>  row = i*64 + (tid>>3),
  //   srcCol = ((tid&7)<<4) ^ (((tid>>3)&7)<<4),  dst = i*8192 + ((tid&~63)<<4)
  const int stRB  = tid >> 3;                                 // 0..63
  const int stCo  = ((tid & 7) << 4) ^ ((stRB & 7) << 4);
  const int stD0  = (tid & ~63) << 4;

  auto STAGE = [&](char* Ad, char* Bd, int s) {
    int cc = s >> 2, kb = s & 3;
    const int cBase = split * SPLC + cc * BN;
    #pragma unroll
    for (int i = 0; i < 4; i++) {
      int row = i * 64 + stRB;
      gload16((const char*)A_h + (((size_t)(rowBase + row)) << 9) + (kb << 7) + stCo,
              Ad + stD0 + i * 8192);
      gload16((const char*)E_h + (((size_t)(cBase + row)) << 9) + (kb << 7) + stCo,
              Bd + stD0 + i * 8192);
    }
  };

  // ---- prologue ----
  if (tid == 0) lcnt = 0;
  const float rc = fmaf(MARG_COEF * __uint_as_float(miscR[4]),
                        __uint_as_float(miscR[2]), MARG_ABS);   // global margin
  float runm[2][16];
  #pragma unroll
  for (int fm = 0; fm < 2; fm++)
    #pragma unroll
    for (int rg = 0; rg < 16; rg++) runm[fm][rg] = INFINITY;
  unsigned segOff = 0;

  STAGE(As0, Bs0, 0);

  f32x16 acc[2][4];
  #pragma unroll
  for (int i = 0; i < 2; i++)
    #pragma unroll
    for (int j = 0; j < 4; j++) acc[i][j] = (f32x16)(0.0f);

  __syncthreads();   // step-0 stage landed

  for (int s = 0; s < NSTEP; ++s) {
    char* Ac = (s & 1) ? As1 : As0;
    char* Bc = (s & 1) ? Bs1 : Bs0;
    if (s + 1 < NSTEP) STAGE((s & 1) ? As0 : As1, (s & 1) ? Bs0 : Bs1, s + 1);

    #pragma unroll
    for (int ks = 0; ks < 4; ++ks) {
      const int off = Ccom ^ (ks << 5);
      bf16x8 a0 = *(const bf16x8*)(Ac + Aoff + off);
      bf16x8 a1 = *(const bf16x8*)(Ac + Aoff + 4096 + off);
      bf16x8 b0 = *(const bf16x8*)(Bc + Boff + off);
      bf16x8 b1 = *(const bf16x8*)(Bc + Boff + 4096 + off);
      bf16x8 b2 = *(const bf16x8*)(Bc + Boff + 8192 + off);
      bf16x8 b3 = *(const bf16x8*)(Bc + Boff + 12288 + off);
      acc[0][0] = __builtin_amdgcn_mfma_f32_32x32x16_bf16(a0, b0, acc[0][0], 0, 0, 0);
      acc[1][0] = __builtin_amdgcn_mfma_f32_32x32x16_bf16(a1, b0, acc[1][0], 0, 0, 0);
      acc[0][1] = __builtin_amdgcn_mfma_f32_32x32x16_bf16(a0, b1, acc[0][1], 0, 0, 0);
      acc[1][1] = __builtin_amdgcn_mfma_f32_32x32x16_bf16(a1, b1, acc[1][1], 0, 0, 0);
      acc[0][2] = __builtin_amdgcn_mfma_f32_32x32x16_bf16(a0, b2, acc[0][2], 0, 0, 0);
      acc[1][2] = __builtin_amdgcn_mfma_f32_32x32x16_bf16(a1, b2, acc[1][2], 0, 0, 0);
      acc[0][3] = __builtin_amdgcn_mfma_f32_32x32x16_bf16(a0, b3, acc[0][3], 0, 0, 0);
      acc[1][3] = __builtin_amdgcn_mfma_f32_32x32x16_bf16(a1, b3, acc[1][3], 0, 0, 0);
    }

    if ((s & 3) == 3) {
      const int cc = s >> 2;
      const int cBase = split * SPLC + cc * BN;

      // in-place q transform + running min
      #pragma unroll
      for (int g = 0; g < 4; g++) {
        float e2c = e2g[cBase + wn * 128 + g * 32 + l31];
        #pragma unroll
        for (int fm = 0; fm < 2; fm++)
          #pragma unroll
          for (int rg = 0; rg < 16; rg++) {
            float qv = fmaf(acc[fm][g][rg], -2.0f, e2c);
            acc[fm][g][rg] = qv;
            runm[fm][rg] = fminf(runm[fm][rg], qv);
          }
      }
      // butterfly over the 32 col-lanes -> lane-uniform row min (so far)
      #pragma unroll
      for (int fm = 0; fm < 2; fm++)
        #pragma unroll
        for (int rg = 0; rg < 16; rg++) {
          float v = runm[fm][rg];
          #pragma unroll
          for (int off = 1; off < 32; off <<= 1) v = fminf(v, __shfl_xor(v, off));
          runm[fm][rg] = v;
        }
      // collect with the fresh threshold
      #pragma unroll
      for (int g = 0; g < 4; g++) {
        int col = cBase + wn * 128 + g * 32 + l31;
        #pragma unroll
        for (int fm = 0; fm < 2; fm++)
          #pragma unroll
          for (int rg = 0; rg < 16; rg++) {
            float qv = acc[fm][g][rg];
            if (qv <= runm[fm][rg] + rc) {
              int row = rowBase + wm * 64 + fm * 32 + ((rg & 3) + 8 * (rg >> 2)) + lh4;
              uint2 en = make_uint2((unsigned)((row << 13) | col), __float_as_uint(qv));
              unsigned p = atomicAdd(&lcnt, 1u);
              if (p < LQ) lbuf[p] = en;
              else { unsigned gp = atomicAdd(ovCnt, 1u);
                     if (gp < OVCAP) cand[(size_t)NBLK * SEGQ + gp] = en; }
            }
          }
      }
      #pragma unroll
      for (int i = 0; i < 2; i++)
        #pragma unroll
        for (int j = 0; j < 4; j++) acc[i][j] = (f32x16)(0.0f);
    }

    __syncthreads();   // drains next-step stage; all appends of this chunk done

    if ((s & 3) == 3) {
      // flush lbuf -> private segment (no global counter contention)
      if (tid == 0) {
        unsigned n = lcnt; if (n > LQ) n = LQ;
        lnS = n; lbaseS = segOff; segOff += n; lcnt = 0;
      }
      __syncthreads();
      unsigned n = lnS, base = lbaseS;
      for (unsigned i = tid; i < n; i += 512) {
        unsigned gp = base + i;
        if (gp < SEGQ) cand[(size_t)seg * SEGQ + gp] = lbuf[i];
        else { unsigned op = atomicAdd(ovCnt, 1u);
               if (op < OVCAP) cand[(size_t)NBLK * SEGQ + op] = lbuf[i]; }
      }
      // copies finish before next chunk's appends (>=4 step barriers away)
    }
  }

  // final per-row min (runm lane-uniform after last chunk's butterfly)
  if (l31 == 0) {
    #pragma unroll
    for (int fm = 0; fm < 2; fm++)
      #pragma unroll
      for (int rg = 0; rg < 16; rg++) {
        int row = rowBase + wm * 64 + fm * 32 + ((rg & 3) + 8 * (rg >> 2)) + lh4;
        atomicMin(&rowMinU[row], encf(runm[fm][rg]));
      }
  }
  if (tid == 0) blkCnt[seg] = (segOff > SEGQ) ? SEGQ : segOff;
}

// ---------------------------------------------------------------------------
// filter: re-test stored coarse q against FINAL rowMin + global margin.
// ---------------------------------------------------------------------------
__global__ __launch_bounds__(256) void filter_kernel(const uint2* __restrict__ cand,
                                                     const unsigned* __restrict__ blkCnt,
                                                     unsigned* __restrict__ misc,
                                                     const unsigned* __restrict__ rowMinU,
                                                     unsigned* __restrict__ list2) {
  const float rc = fmaf(MARG_COEF * __uint_as_float(misc[4]),
                        __uint_as_float(misc[2]), MARG_ABS);
  auto test = [&](uint2 en) {
    unsigned row = en.x >> 13;
    float q  = __uint_as_float(en.y);
    float rm = decf(rowMinU[row]);
    if (q <= rm + rc) {
      unsigned p = atomicAdd(&misc[3], 1u);
      if (p < CAP2) list2[p] = en.x;
    }
  };
  unsigned seg = blockIdx.x;               // NBLK blocks
  unsigned n = blkCnt[seg]; if (n > SEGQ) n = SEGQ;
  const uint2* sp = cand + (size_t)seg * SEGQ;
  for (unsigned i = threadIdx.x; i < n; i += 256) test(sp[i]);

  unsigned ov = misc[1]; if (ov > OVCAP) ov = OVCAP;
  const uint2* op = cand + (size_t)NBLK * SEGQ;
  for (unsigned i = blockIdx.x * 256 + threadIdx.x; i < ov; i += NBLK * 256) test(op[i]);
}

// ---------------------------------------------------------------------------
// refine: 16-lane groups, fp64 dot, exact ref combine, u64 atomicMin key.
// ---------------------------------------------------------------------------
__global__ __launch_bounds__(256) void refine_kernel(const float* __restrict__ x,
                                                     const float* __restrict__ embed,
                                                     const float* __restrict__ x2g,
                                                     const float* __restrict__ e2g,
                                                     const unsigned* __restrict__ miscR,
                                                     const unsigned* __restrict__ list2,
                                                     unsigned long long* __restrict__ pKey) {
  const int l16 = threadIdx.x & 15;
  unsigned total = miscR[3]; if (total > CAP2) total = CAP2;
  unsigned gid = (blockIdx.x * 256 + threadIdx.x) >> 4;
  unsigned ng  = (gridDim.x * 256) >> 4;
  for (unsigned i = gid; i < total; i += ng) {
    unsigned pk = list2[i];
    int row = (int)(pk >> 13), col = (int)(pk & 8191u);
    double s = 0.0;
    #pragma unroll
    for (int p = 0; p < 4; p++) {
      float4 xv = *(const float4*)&x[(size_t)row * D + p * 64 + l16 * 4];
      float4 ev = *(const float4*)&embed[(size_t)col * D + p * 64 + l16 * 4];
      s = fma((double)xv.x, (double)ev.x, s);
      s = fma((double)xv.y, (double)ev.y, s);
      s = fma((double)xv.z, (double)ev.z, s);
      s = fma((double)xv.w, (double)ev.w, s);
    }
    #pragma unroll
    for (int off = 1; off < 16; off <<= 1) s += __shfl_xor(s, off);
    if (l16 == 0) {
      float xef = (float)s;
      float ss  = __fadd_rn(x2g[row], e2g[col]);
      float d2  = __fsub_rn(ss, __fmul_rn(2.0f, xef));
      d2 = fmaxf(d2, 0.0f);
      float sq = sqrtf(d2);
      unsigned long long key =
          ((unsigned long long)__float_as_uint(sq) << 32) | (unsigned)col;
      atomicMin(pKey + row, key);
    }
  }
}

// ---------------------------------------------------------------------------
// finalize: gather codes + write index as float.
// ---------------------------------------------------------------------------
__global__ __launch_bounds__(256) void final_kernel(const float* __restrict__ embed,
                                                    const unsigned long long* __restrict__ pKey,
                                                    float* __restrict__ outQ,
                                                    float* __restrict__ indF) {
  int wid  = threadIdx.x >> 6;
  int lane = threadIdx.x & 63;
  int row  = blockIdx.x * 4 + wid;
  unsigned long long k = pKey[row];
  int idx = (int)(k & 8191ull);
  float4 v = *(const float4*)&embed[(size_t)idx * D + lane * 4];
  *(float4*)&outQ[(size_t)row * D + lane * 4] = v;
  if (lane == 0) indF[row] = (float)idx;
}

// ===========================================================================
// Fallback fp32 path (round-1, proven) — used if ws_size < WS_NEED.
// ===========================================================================
#define BM_F 128
#define BN_F 128
#define BK_F 32
#define NSPLIT_F 4
#define SPLIT_CF (CODES / NSPLIT_F)

__global__ __launch_bounds__(256) void sq_kernel(const float* __restrict__ x,
                                                 const float* __restrict__ embed,
                                                 float* __restrict__ x2,
                                                 float* __restrict__ e2) {
  int wid  = threadIdx.x >> 6;
  int lane = threadIdx.x & 63;
  int rid  = blockIdx.x * 4 + wid;
  const float* base = (rid < NROWS) ? (x + (size_t)rid * D)
                                    : (embed + (size_t)(rid - NROWS) * D);
  float4 v = *(const float4*)(base + lane * 4);
  float p = v.x * v.x + v.y * v.y + v.z * v.z + v.w * v.w;
  #pragma unroll
  for (int off = 32; off > 0; off >>= 1) p += __shfl_down(p, off);
  if (lane == 0) {
    if (rid < NROWS) x2[rid] = p;
    else             e2[rid - NROWS] = p;
  }
}

__global__ __launch_bounds__(256) void argmin_f32_kernel(const float* __restrict__ x,
                                                         const float* __restrict__ embed,
                                                         const float* __restrict__ x2,
                                                         const float* __restrict__ e2,
                                                         float* __restrict__ pVal,
                                                         int* __restrict__ pIdx) {
  __shared__ float As[BK_F][BM_F];
  __shared__ float Bs[BK_F][BN_F];
  const int tid = threadIdx.x;
  const int ty = tid >> 4, tx = tid & 15;
  const int rowBase = blockIdx.x * BM_F;
  const int split = blockIdx.y;
  const int r0 = ty * 8, c0 = tx * 8;
  float bestV[8]; int bestI[8];
  #pragma unroll
  for (int i = 0; i < 8; i++) { bestV[i] = -INFINITY; bestI[i] = 0; }
  float x2r[8];
  #pragma unroll
  for (int i = 0; i < 8; i++) x2r[i] = x2[rowBase + r0 + i];
  for (int chunk = 0; chunk < SPLIT_CF / BN_F; ++chunk) {
    const int cBase = split * SPLIT_CF + chunk * BN_F;
    float acc[8][8];
    #pragma unroll
    for (int i = 0; i < 8; i++)
      #pragma unroll
      for (int j = 0; j < 8; j++) acc[i][j] = 0.0f;
    for (int kb = 0; kb < D / BK_F; ++kb) {
      #pragma unroll
      for (int i = 0; i < 4; i++) {
        int f4 = tid + i * 256;
        int rr = f4 >> 3, k4 = f4 & 7;
        float4 va = *(const float4*)&x[(size_t)(rowBase + rr) * D + kb * BK_F + k4 * 4];
        As[k4 * 4 + 0][rr] = va.x; As[k4 * 4 + 1][rr] = va.y;
        As[k4 * 4 + 2][rr] = va.z; As[k4 * 4 + 3][rr] = va.w;
        float4 vb = *(const float4*)&embed[(size_t)(cBase + rr) * D + kb * BK_F + k4 * 4];
        Bs[k4 * 4 + 0][rr] = vb.x; Bs[k4 * 4 + 1][rr] = vb.y;
        Bs[k4 * 4 + 2][rr] = vb.z; Bs[k4 * 4 + 3][rr] = vb.w;
      }
      __syncthreads();
      #pragma unroll 8
      for (int kk = 0; kk < BK_F; kk++) {
        float a[8], b[8];
        *(float4*)&a[0] = *(const float4*)&As[kk][r0];
        *(float4*)&a[4] = *(const float4*)&As[kk][r0 + 4];
        *(float4*)&b[0] = *(const float4*)&Bs[kk][c0];
        *(float4*)&b[4] = *(const float4*)&Bs[kk][c0 + 4];
        #pragma unroll
        for (int i = 0; i < 8; i++)
          #pragma unroll
          for (int j = 0; j < 8; j++)
            acc[i][j] = fmaf(a[i], b[j], acc[i][j]);
      }
      __syncthreads();
    }
    #pragma unroll
    for (int j = 0; j < 8; j++) {
      int c = cBase + c0 + j;
      float e2c = e2[c];
      #pragma unroll
      for (int i = 0; i < 8; i++) {
        float s  = __fadd_rn(x2r[i], e2c);
        float u  = __fmul_rn(2.0f, acc[i][j]);
        float d2 = fmaxf(__fsub_rn(s, u), 0.0f);
        float dist = -sqrtf(d2);
        if (dist > bestV[i]) { bestV[i] = dist; bestI[i] = c; }
      }
    }
  }
  __syncthreads();
  float* Vl = &As[0][0];
  int*   Il = (int*)&Bs[0][0];
  #pragma unroll
  for (int i = 0; i < 8; i++) {
    Vl[(ty * 16 + tx) * 8 + i] = bestV[i];
    Il[(ty * 16 + tx) * 8 + i] = bestI[i];
  }
  __syncthreads();
  if (tid < BM_F) {
    int rr = tid, tyr = rr >> 3, ii = rr & 7;
    float bv = -INFINITY; int bi = 0;
    #pragma unroll
    for (int t = 0; t < 16; t++) {
      float v = Vl[(tyr * 16 + t) * 8 + ii];
      int  iv = Il[(tyr * 16 + t) * 8 + ii];
      if (v > bv || (v == bv && iv < bi)) { bv = v; bi = iv; }
    }
    pVal[split * NROWS + rowBase + rr] = bv;
    pIdx[split * NROWS + rowBase + rr] = bi;
  }
}

__global__ __launch_bounds__(256) void merge_f32_kernel(const float* __restrict__ pVal,
                                                        const int* __restrict__ pIdx,
                                                        float* __restrict__ indF) {
  int row = blockIdx.x * 256 + threadIdx.x;
  if (row >= NROWS) return;
  float bv = -INFINITY; int bi = 0;
  #pragma unroll
  for (int s = 0; s < NSPLIT_F; s++) {
    float v = pVal[s * NROWS + row];
    int  iv = pIdx[s * NROWS + row];
    if (v > bv || (v == bv && iv < bi)) { bv = v; bi = iv; }
  }
  indF[row] = (float)bi;
}

__global__ __launch_bounds__(256) void gather_f32_kernel(const float* __restrict__ embed,
                                                         const float* __restrict__ indF,
                                                         float* __restrict__ outQ) {
  int wid = threadIdx.x >> 6, lane = threadIdx.x & 63;
  int row = blockIdx.x * 4 + wid;
  int idx = (int)indF[row];
  float4 v = *(const float4*)&embed[(size_t)idx * D + lane * 4];
  *(float4*)&outQ[(size_t)row * D + lane * 4] = v;
}

// ---------------------------------------------------------------------------
extern "C" void kernel_launch(void* const* d_in, const int* in_sizes, int n_in,
                              void* d_out, int out_size, void* d_ws, size_t ws_size,
                              hipStream_t stream) {
  const float* x     = (const float*)d_in[0];
  const float* embed = (const float*)d_in[1];
  float* o = (float*)d_out;

  if (ws_size >= WS_NEED) {
    char* w = (char*)d_ws;
    unsigned short* A_h = (unsigned short*)(w + OFF_AH);
    float* x2 = (float*)(w + OFF_X2);
    float* nx = (float*)(w + OFF_NX);
    float* e2 = (float*)(w + OFF_E2);
    unsigned* rowMinU = (unsigned*)(w + OFF_RM);
    unsigned long long* pKey = (unsigned long long*)(w + OFF_PK);
    unsigned* misc = (unsigned*)(w + OFF_MISC);
    unsigned* blkCnt = (unsigned*)(w + OFF_BCNT);
    unsigned* list2 = (unsigned*)(w + OFF_L2);
    uint2* cand = (uint2*)(w + OFF_CAND);

    unsigned short* E_h = (unsigned short*)o;      // 4MB scratch in quantize region
    float* indF = o + QOFF;

    init_kernel<<<128, 256, 0, stream>>>(misc, rowMinU, pKey);
    prep_kernel<<<(NROWS + CODES) / 4, 256, 0, stream>>>(x, embed, A_h, E_h, x2, nx, e2, misc);
    dim3 gridC(NROWS / BM, NSPL);
    gemm_coarse<<<gridC, 512, 0, stream>>>(A_h, E_h, e2, misc, rowMinU,
                                           cand, blkCnt, &misc[1]);
    filter_kernel<<<NBLK, 256, 0, stream>>>(cand, blkCnt, misc, rowMinU, list2);
    refine_kernel<<<1024, 256, 0, stream>>>(x, embed, x2, e2, misc, list2, pKey);
    final_kernel<<<NROWS / 4, 256, 0, stream>>>(embed, pKey, o, indF);
  } else {
    // ---- fp32 fallback ----
    float* x2   = o;
    float* e2   = o + 32768;
    float* pVal = o + 65536;
    int*   pIdx = (int*)(o + 196608);
    float* indF = o + QOFF;
    sq_kernel<<<(NROWS + CODES) / 4, 256, 0, stream>>>(x, embed, x2, e2);
    dim3 gridB(NROWS / BM_F, NSPLIT_F);
    argmin_f32_kernel<<<gridB, 256, 0, stream>>>(x, embed, x2, e2, pVal, pIdx);
    merge_f32_kernel<<<NROWS / 256, 256, 0, stream>>>(pVal, pIdx, indF);
    gather_f32_kernel<<<NROWS / 4, 256, 0, stream>>>(embed, indF, o);
  }
}

// Round 15
// 1063.618 us; speedup vs baseline: 1.1117x; 1.1117x over previous
//
#include <hip/hip_runtime.h>
#include <math.h>

#define D       256
#define NROWS   32768      // 8 * 4096
#define CODES   8192
#define QOFF    8388608    // index output offset (floats) in d_out

// ---------------- coarse GEMM config (round-8 engine: fits registers) ------
#define BM      128
#define BN      128
#define NSPL    4
#define SPLC    (CODES / NSPL)    // 2048
#define NCHUNK  (SPLC / BN)       // 16
#define NSTEP   (NCHUNK * 4)      // 64 kb-steps (BK=64)
#define NBLK    1024              // 256 rowTiles * NSPL
#define LQ      1536              // LDS candidate buffer entries (per chunk)
#define SEGQ    3072u             // per-block candidate segment entries (8B)
#define OVCAP   262144u
#define CAP2    1048576u

// rigorous collect margin (2M): 2*2*(2u+u^2)*||x||max*||e||max, u=2^-9 (bf16 rn)
#define MARG_COEF 0.016f
#define MARG_ABS  0.10f

// ---------------- ws layout (bytes) ----------------
#define OFF_AH    0ull               // 16,777,216
#define OFF_X2    16777216ull
#define OFF_NX    16908288ull
#define OFF_E2    17039360ull
#define OFF_RM    17072128ull        // monotone-encoded float bits
#define OFF_PK    17203200ull
#define OFF_MISC  17465344ull        // [1]=ovCnt [2]=neMaxBits [3]=survCnt [4]=nxMaxBits
#define OFF_BCNT  17465600ull
#define OFF_L2    17469696ull        // CAP2 * 4
#define OFF_CAND  21664000ull        // uint2: NBLK*SEGQ segs + OVCAP overflow
#define WS_NEED   48926976ull        // < 51,019,776 proven in round 2

typedef __attribute__((ext_vector_type(8)))  short bf16x8;
typedef __attribute__((ext_vector_type(16))) float f32x16;

__device__ __forceinline__ void gload16(const void* g, void* l) {
  __builtin_amdgcn_global_load_lds(
      (const __attribute__((address_space(1))) unsigned int*)g,
      (__attribute__((address_space(3))) unsigned int*)l, 16, 0, 0);
}

__device__ __forceinline__ unsigned short bf16rn(float x) {
  unsigned u = __float_as_uint(x);
  return (unsigned short)((u + 0x7fffu + ((u >> 16) & 1u)) >> 16);
}

// monotone float <-> uint (order-preserving incl. negatives)
__device__ __forceinline__ unsigned encf(float f) {
  unsigned b = __float_as_uint(f);
  return (b >> 31) ? ~b : (b | 0x80000000u);
}
__device__ __forceinline__ float decf(unsigned u) {
  return __uint_as_float((u >> 31) ? (u ^ 0x80000000u) : ~u);
}

// ---------------------------------------------------------------------------
__global__ __launch_bounds__(256) void init_kernel(unsigned* __restrict__ misc,
                                                   unsigned* __restrict__ rowMinU,
                                                   unsigned long long* __restrict__ pKey) {
  int i = blockIdx.x * 256 + threadIdx.x;   // 32768
  if (i < 16) misc[i] = 0u;
  rowMinU[i] = 0xFFFFFFFFu;
  pKey[i] = ~0ull;
}

// ---------------------------------------------------------------------------
// prep: bf16 h-planes + squared norms + neMax + nxMax.
// ---------------------------------------------------------------------------
__global__ __launch_bounds__(256) void prep_kernel(const float* __restrict__ x,
                                                   const float* __restrict__ embed,
                                                   unsigned short* __restrict__ A_h,
                                                   unsigned short* __restrict__ E_h,
                                                   float* __restrict__ x2,
                                                   float* __restrict__ nx,
                                                   float* __restrict__ e2,
                                                   unsigned* __restrict__ misc) {
  int wid  = threadIdx.x >> 6;
  int lane = threadIdx.x & 63;
  int rid  = blockIdx.x * 4 + wid;   // 0..40959
  const float* src;
  unsigned short* dst;
  if (rid < NROWS) { src = x + (size_t)rid * D;               dst = A_h + (size_t)rid * D; }
  else             { src = embed + (size_t)(rid - NROWS) * D; dst = E_h + (size_t)(rid - NROWS) * D; }
  float4 v = *(const float4*)(src + lane * 4);
  ushort4 hv = make_ushort4(bf16rn(v.x), bf16rn(v.y), bf16rn(v.z), bf16rn(v.w));
  *(ushort4*)(dst + lane * 4) = hv;
  float p = v.x * v.x + v.y * v.y + v.z * v.z + v.w * v.w;
  #pragma unroll
  for (int off = 32; off > 0; off >>= 1) p += __shfl_down(p, off);
  if (lane == 0) {
    float n = sqrtf(p);
    if (rid < NROWS) { x2[rid] = p; nx[rid] = n; atomicMax(&misc[4], __float_as_uint(n)); }
    else { e2[rid - NROWS] = p; atomicMax(&misc[2], __float_as_uint(n)); }
  }
}

// ---------------------------------------------------------------------------
// Fused coarse pass on the ROUND-8 engine (128x128 tile, 4 waves 2x2, wave
// tile 64x64 = acc[2][2] -> only 64 AGPR, ~100 VGPR: fits the 256-reg budget
// at 2 waves/SIMD with ~90 regs spare -- rounds 12-14 spilled because the
// 256x256 engine's acc[2][4]=128 AGPR left no room for the fusion state).
// Per chunk: in-place q transform (acc = e2-2*xe) + running row-min
// (+ l31 butterfly) then collect acc <= runm + rc (global scalar margin)
// into LDS, flushed per chunk to a private per-block segment.
// Superset proof: runm_t >= rowMin_final => anything passing the final
// threshold also passes here; filter reduces to the proven survivor set.
// ---------------------------------------------------------------------------
__global__ __launch_bounds__(256, 2) void gemm_coarse(
    const unsigned short* __restrict__ A_h,
    const unsigned short* __restrict__ E_h,
    const float* __restrict__ e2g,
    const unsigned* __restrict__ miscR,
    unsigned* __restrict__ rowMinU,
    uint2* __restrict__ cand,           // NBLK*SEGQ segments + OVCAP tail
    unsigned* __restrict__ blkCnt,
    unsigned* __restrict__ ovCnt) {     // &misc[1]
  __shared__ __align__(16) char As0[16384];   // 128 rows x 128B (BK=64)
  __shared__ __align__(16) char As1[16384];
  __shared__ __align__(16) char Bs0[16384];
  __shared__ __align__(16) char Bs1[16384];
  __shared__ uint2 lbuf[LQ];                  // 12KB
  __shared__ unsigned lcnt, lnS, lbaseS;

  const int tid  = threadIdx.x;
  const int lane = tid & 63;
  const int wave = tid >> 6;            // 0..3
  const int wm = wave >> 1;             // 0..1  row group (64 rows)
  const int wn = wave & 1;              // 0..1  col group (64 cols)
  const int l31 = lane & 31;
  const int hi16 = (lane >> 5) << 4;
  const int lh4  = (lane >> 5) << 2;
  const int rowBase = blockIdx.x * BM;
  const int split   = blockIdx.y;
  const int seg     = blockIdx.y * 256 + blockIdx.x;

  // per-lane read geometry: frag row&7 == l31&7 for both A and B.
  const int Ccom = hi16 ^ ((l31 & 7) << 4);
  const int Aoff = (wm * 64 + l31) << 7;    // + f*4096 + (Ccom^ks*32)
  const int Boff = (wn * 64 + l31) << 7;    // + g*4096 + (Ccom^ks*32)

  // staging addressing (algebraic form of SWK, 3 registers):
  //   q=i*256+tid: row=i*32+(tid>>3), srcCol=((tid&7)<<4)^(((tid>>3)&7)<<4),
  //   dst=i*4096+((tid&~63)<<4)
  const int stRB = tid >> 3;                                  // 0..31
  const int stCo = ((tid & 7) << 4) ^ ((stRB & 7) << 4);
  const int stD0 = (tid & ~63) << 4;

  auto STAGE = [&](char* Ad, char* Bd, int s) {
    int cc = s >> 2, kb = s & 3;
    const int cBase = split * SPLC + cc * BN;
    #pragma unroll
    for (int i = 0; i < 4; i++) {
      int row = i * 32 + stRB;
      gload16((const char*)A_h + (((size_t)(rowBase + row)) << 9) + (kb << 7) + stCo,
              Ad + stD0 + i * 4096);
      gload16((const char*)E_h + (((size_t)(cBase + row)) << 9) + (kb << 7) + stCo,
              Bd + stD0 + i * 4096);
    }
  };

  // ---- prologue ----
  if (tid == 0) lcnt = 0;
  const float rc = fmaf(MARG_COEF * __uint_as_float(miscR[4]),
                        __uint_as_float(miscR[2]), MARG_ABS);   // global margin
  float runm[2][16];
  #pragma unroll
  for (int fm = 0; fm < 2; fm++)
    #pragma unroll
    for (int rg = 0; rg < 16; rg++) runm[fm][rg] = INFINITY;
  unsigned segOff = 0;

  STAGE(As0, Bs0, 0);

  f32x16 acc[2][2];
  #pragma unroll
  for (int i = 0; i < 2; i++)
    #pragma unroll
    for (int j = 0; j < 2; j++) acc[i][j] = (f32x16)(0.0f);

  __syncthreads();   // step-0 stage landed

  for (int s = 0; s < NSTEP; ++s) {
    char* Ac = (s & 1) ? As1 : As0;
    char* Bc = (s & 1) ? Bs1 : Bs0;
    if (s + 1 < NSTEP) STAGE((s & 1) ? As0 : As1, (s & 1) ? Bs0 : Bs1, s + 1);

    #pragma unroll
    for (int ks = 0; ks < 4; ++ks) {
      const int off = Ccom ^ (ks << 5);
      bf16x8 a0 = *(const bf16x8*)(Ac + Aoff + off);
      bf16x8 a1 = *(const bf16x8*)(Ac + Aoff + 4096 + off);
      bf16x8 b0 = *(const bf16x8*)(Bc + Boff + off);
      bf16x8 b1 = *(const bf16x8*)(Bc + Boff + 4096 + off);
      acc[0][0] = __builtin_amdgcn_mfma_f32_32x32x16_bf16(a0, b0, acc[0][0], 0, 0, 0);
      acc[1][0] = __builtin_amdgcn_mfma_f32_32x32x16_bf16(a1, b0, acc[1][0], 0, 0, 0);
      acc[0][1] = __builtin_amdgcn_mfma_f32_32x32x16_bf16(a0, b1, acc[0][1], 0, 0, 0);
      acc[1][1] = __builtin_amdgcn_mfma_f32_32x32x16_bf16(a1, b1, acc[1][1], 0, 0, 0);
    }

    if ((s & 3) == 3) {
      const int cc = s >> 2;
      const int cBase = split * SPLC + cc * BN;

      // in-place q transform + running min
      #pragma unroll
      for (int g = 0; g < 2; g++) {
        float e2c = e2g[cBase + wn * 64 + g * 32 + l31];
        #pragma unroll
        for (int fm = 0; fm < 2; fm++)
          #pragma unroll
          for (int rg = 0; rg < 16; rg++) {
            float qv = fmaf(acc[fm][g][rg], -2.0f, e2c);
            acc[fm][g][rg] = qv;
            runm[fm][rg] = fminf(runm[fm][rg], qv);
          }
      }
      // butterfly over the 32 col-lanes -> lane-uniform row min (so far)
      #pragma unroll
      for (int fm = 0; fm < 2; fm++)
        #pragma unroll
        for (int rg = 0; rg < 16; rg++) {
          float v = runm[fm][rg];
          #pragma unroll
          for (int off = 1; off < 32; off <<= 1) v = fminf(v, __shfl_xor(v, off));
          runm[fm][rg] = v;
        }
      // collect with the fresh threshold
      #pragma unroll
      for (int g = 0; g < 2; g++) {
        int col = cBase + wn * 64 + g * 32 + l31;
        #pragma unroll
        for (int fm = 0; fm < 2; fm++)
          #pragma unroll
          for (int rg = 0; rg < 16; rg++) {
            float qv = acc[fm][g][rg];
            if (qv <= runm[fm][rg] + rc) {
              int row = rowBase + wm * 64 + fm * 32 + ((rg & 3) + 8 * (rg >> 2)) + lh4;
              uint2 en = make_uint2((unsigned)((row << 13) | col), __float_as_uint(qv));
              unsigned p = atomicAdd(&lcnt, 1u);
              if (p < LQ) lbuf[p] = en;
              else { unsigned gp = atomicAdd(ovCnt, 1u);
                     if (gp < OVCAP) cand[(size_t)NBLK * SEGQ + gp] = en; }
            }
          }
      }
      #pragma unroll
      for (int i = 0; i < 2; i++)
        #pragma unroll
        for (int j = 0; j < 2; j++) acc[i][j] = (f32x16)(0.0f);
    }

    __syncthreads();   // drains next-step stage; all appends of this chunk done

    if ((s & 3) == 3) {
      // flush lbuf -> private segment (no global counter contention)
      if (tid == 0) {
        unsigned n = lcnt; if (n > LQ) n = LQ;
        lnS = n; lbaseS = segOff; segOff += n; lcnt = 0;
      }
      __syncthreads();
      unsigned n = lnS, base = lbaseS;
      for (unsigned i = tid; i < n; i += 256) {
        unsigned gp = base + i;
        if (gp < SEGQ) cand[(size_t)seg * SEGQ + gp] = lbuf[i];
        else { unsigned op = atomicAdd(ovCnt, 1u);
               if (op < OVCAP) cand[(size_t)NBLK * SEGQ + op] = lbuf[i]; }
      }
      // copies finish before next chunk's appends (>=4 step barriers away)
    }
  }

  // final per-row min (runm lane-uniform after last chunk's butterfly)
  if (l31 == 0) {
    #pragma unroll
    for (int fm = 0; fm < 2; fm++)
      #pragma unroll
      for (int rg = 0; rg < 16; rg++) {
        int row = rowBase + wm * 64 + fm * 32 + ((rg & 3) + 8 * (rg >> 2)) + lh4;
        atomicMin(&rowMinU[row], encf(runm[fm][rg]));
      }
  }
  if (tid == 0) blkCnt[seg] = (segOff > SEGQ) ? SEGQ : segOff;
}

// ---------------------------------------------------------------------------
// filter: re-test stored coarse q against FINAL rowMin + global margin.
// ---------------------------------------------------------------------------
__global__ __launch_bounds__(256) void filter_kernel(const uint2* __restrict__ cand,
                                                     const unsigned* __restrict__ blkCnt,
                                                     unsigned* __restrict__ misc,
                                                     const unsigned* __restrict__ rowMinU,
                                                     unsigned* __restrict__ list2) {
  const float rc = fmaf(MARG_COEF * __uint_as_float(misc[4]),
                        __uint_as_float(misc[2]), MARG_ABS);
  auto test = [&](uint2 en) {
    unsigned row = en.x >> 13;
    float q  = __uint_as_float(en.y);
    float rm = decf(rowMinU[row]);
    if (q <= rm + rc) {
      unsigned p = atomicAdd(&misc[3], 1u);
      if (p < CAP2) list2[p] = en.x;
    }
  };
  unsigned seg = blockIdx.x;               // NBLK blocks
  unsigned n = blkCnt[seg]; if (n > SEGQ) n = SEGQ;
  const uint2* sp = cand + (size_t)seg * SEGQ;
  for (unsigned i = threadIdx.x; i < n; i += 256) test(sp[i]);

  unsigned ov = misc[1]; if (ov > OVCAP) ov = OVCAP;
  const uint2* op = cand + (size_t)NBLK * SEGQ;
  for (unsigned i = blockIdx.x * 256 + threadIdx.x; i < ov; i += NBLK * 256) test(op[i]);
}

// ---------------------------------------------------------------------------
// refine: 16-lane groups, fp64 dot, exact ref combine, u64 atomicMin key.
// ---------------------------------------------------------------------------
__global__ __launch_bounds__(256) void refine_kernel(const float* __restrict__ x,
                                                     const float* __restrict__ embed,
                                                     const float* __restrict__ x2g,
                                                     const float* __restrict__ e2g,
                                                     const unsigned* __restrict__ miscR,
                                                     const unsigned* __restrict__ list2,
                                                     unsigned long long* __restrict__ pKey) {
  const int l16 = threadIdx.x & 15;
  unsigned total = miscR[3]; if (total > CAP2) total = CAP2;
  unsigned gid = (blockIdx.x * 256 + threadIdx.x) >> 4;
  unsigned ng  = (gridDim.x * 256) >> 4;
  for (unsigned i = gid; i < total; i += ng) {
    unsigned pk = list2[i];
    int row = (int)(pk >> 13), col = (int)(pk & 8191u);
    double s = 0.0;
    #pragma unroll
    for (int p = 0; p < 4; p++) {
      float4 xv = *(const float4*)&x[(size_t)row * D + p * 64 + l16 * 4];
      float4 ev = *(const float4*)&embed[(size_t)col * D + p * 64 + l16 * 4];
      s = fma((double)xv.x, (double)ev.x, s);
      s = fma((double)xv.y, (double)ev.y, s);
      s = fma((double)xv.z, (double)ev.z, s);
      s = fma((double)xv.w, (double)ev.w, s);
    }
    #pragma unroll
    for (int off = 1; off < 16; off <<= 1) s += __shfl_xor(s, off);
    if (l16 == 0) {
      float xef = (float)s;
      float ss  = __fadd_rn(x2g[row], e2g[col]);
      float d2  = __fsub_rn(ss, __fmul_rn(2.0f, xef));
      d2 = fmaxf(d2, 0.0f);
      float sq = sqrtf(d2);
      unsigned long long key =
          ((unsigned long long)__float_as_uint(sq) << 32) | (unsigned)col;
      atomicMin(pKey + row, key);
    }
  }
}

// ---------------------------------------------------------------------------
// finalize: gather codes + write index as float.
// ---------------------------------------------------------------------------
__global__ __launch_bounds__(256) void final_kernel(const float* __restrict__ embed,
                                                    const unsigned long long* __restrict__ pKey,
                                                    float* __restrict__ outQ,
                                                    float* __restrict__ indF) {
  int wid  = threadIdx.x >> 6;
  int lane = threadIdx.x & 63;
  int row  = blockIdx.x * 4 + wid;
  unsigned long long k = pKey[row];
  int idx = (int)(k & 8191ull);
  float4 v = *(const float4*)&embed[(size_t)idx * D + lane * 4];
  *(float4*)&outQ[(size_t)row * D + lane * 4] = v;
  if (lane == 0) indF[row] = (float)idx;
}

// ===========================================================================
// Fallback fp32 path (round-1, proven) — used if ws_size < WS_NEED.
// ===========================================================================
#define BM_F 128
#define BN_F 128
#define BK_F 32
#define NSPLIT_F 4
#define SPLIT_CF (CODES / NSPLIT_F)

__global__ __launch_bounds__(256) void sq_kernel(const float* __restrict__ x,
                                                 const float* __restrict__ embed,
                                                 float* __restrict__ x2,
                                                 float* __restrict__ e2) {
  int wid  = threadIdx.x >> 6;
  int lane = threadIdx.x & 63;
  int rid  = blockIdx.x * 4 + wid;
  const float* base = (rid < NROWS) ? (x + (size_t)rid * D)
                                    : (embed + (size_t)(rid - NROWS) * D);
  float4 v = *(const float4*)(base + lane * 4);
  float p = v.x * v.x + v.y * v.y + v.z * v.z + v.w * v.w;
  #pragma unroll
  for (int off = 32; off > 0; off >>= 1) p += __shfl_down(p, off);
  if (lane == 0) {
    if (rid < NROWS) x2[rid] = p;
    else             e2[rid - NROWS] = p;
  }
}

__global__ __launch_bounds__(256) void argmin_f32_kernel(const float* __restrict__ x,
                                                         const float* __restrict__ embed,
                                                         const float* __restrict__ x2,
                                                         const float* __restrict__ e2,
                                                         float* __restrict__ pVal,
                                                         int* __restrict__ pIdx) {
  __shared__ float As[BK_F][BM_F];
  __shared__ float Bs[BK_F][BN_F];
  const int tid = threadIdx.x;
  const int ty = tid >> 4, tx = tid & 15;
  const int rowBase = blockIdx.x * BM_F;
  const int split = blockIdx.y;
  const int r0 = ty * 8, c0 = tx * 8;
  float bestV[8]; int bestI[8];
  #pragma unroll
  for (int i = 0; i < 8; i++) { bestV[i] = -INFINITY; bestI[i] = 0; }
  float x2r[8];
  #pragma unroll
  for (int i = 0; i < 8; i++) x2r[i] = x2[rowBase + r0 + i];
  for (int chunk = 0; chunk < SPLIT_CF / BN_F; ++chunk) {
    const int cBase = split * SPLIT_CF + chunk * BN_F;
    float acc[8][8];
    #pragma unroll
    for (int i = 0; i < 8; i++)
      #pragma unroll
      for (int j = 0; j < 8; j++) acc[i][j] = 0.0f;
    for (int kb = 0; kb < D / BK_F; ++kb) {
      #pragma unroll
      for (int i = 0; i < 4; i++) {
        int f4 = tid + i * 256;
        int rr = f4 >> 3, k4 = f4 & 7;
        float4 va = *(const float4*)&x[(size_t)(rowBase + rr) * D + kb * BK_F + k4 * 4];
        As[k4 * 4 + 0][rr] = va.x; As[k4 * 4 + 1][rr] = va.y;
        As[k4 * 4 + 2][rr] = va.z; As[k4 * 4 + 3][rr] = va.w;
        float4 vb = *(const float4*)&embed[(size_t)(cBase + rr) * D + kb * BK_F + k4 * 4];
        Bs[k4 * 4 + 0][rr] = vb.x; Bs[k4 * 4 + 1][rr] = vb.y;
        Bs[k4 * 4 + 2][rr] = vb.z; Bs[k4 * 4 + 3][rr] = vb.w;
      }
      __syncthreads();
      #pragma unroll 8
      for (int kk = 0; kk < BK_F; kk++) {
        float a[8], b[8];
        *(float4*)&a[0] = *(const float4*)&As[kk][r0];
        *(float4*)&a[4] = *(const float4*)&As[kk][r0 + 4];
        *(float4*)&b[0] = *(const float4*)&Bs[kk][c0];
        *(float4*)&b[4] = *(const float4*)&Bs[kk][c0 + 4];
        #pragma unroll
        for (int i = 0; i < 8; i++)
          #pragma unroll
          for (int j = 0; j < 8; j++)
            acc[i][j] = fmaf(a[i], b[j], acc[i][j]);
      }
      __syncthreads();
    }
    #pragma unroll
    for (int j = 0; j < 8; j++) {
      int c = cBase + c0 + j;
      float e2c = e2[c];
      #pragma unroll
      for (int i = 0; i < 8; i++) {
        float s  = __fadd_rn(x2r[i], e2c);
        float u  = __fmul_rn(2.0f, acc[i][j]);
        float d2 = fmaxf(__fsub_rn(s, u), 0.0f);
        float dist = -sqrtf(d2);
        if (dist > bestV[i]) { bestV[i] = dist; bestI[i] = c; }
      }
    }
  }
  __syncthreads();
  float* Vl = &As[0][0];
  int*   Il = (int*)&Bs[0][0];
  #pragma unroll
  for (int i = 0; i < 8; i++) {
    Vl[(ty * 16 + tx) * 8 + i] = bestV[i];
    Il[(ty * 16 + tx) * 8 + i] = bestI[i];
  }
  __syncthreads();
  if (tid < BM_F) {
    int rr = tid, tyr = rr >> 3, ii = rr & 7;
    float bv = -INFINITY; int bi = 0;
    #pragma unroll
    for (int t = 0; t < 16; t++) {
      float v = Vl[(tyr * 16 + t) * 8 + ii];
      int  iv = Il[(tyr * 16 + t) * 8 + ii];
      if (v > bv || (v == bv && iv < bi)) { bv = v; bi = iv; }
    }
    pVal[split * NROWS + rowBase + rr] = bv;
    pIdx[split * NROWS + rowBase + rr] = bi;
  }
}

__global__ __launch_bounds__(256) void merge_f32_kernel(const float* __restrict__ pVal,
                                                        const int* __restrict__ pIdx,
                                                        float* __restrict__ indF) {
  int row = blockIdx.x * 256 + threadIdx.x;
  if (row >= NROWS) return;
  float bv = -INFINITY; int bi = 0;
  #pragma unroll
  for (int s = 0; s < NSPLIT_F; s++) {
    float v = pVal[s * NROWS + row];
    int  iv = pIdx[s * NROWS + row];
    if (v > bv || (v == bv && iv < bi)) { bv = v; bi = iv; }
  }
  indF[row] = (float)bi;
}

__global__ __launch_bounds__(256) void gather_f32_kernel(const float* __restrict__ embed,
                                                         const float* __restrict__ indF,
                                                         float* __restrict__ outQ) {
  int wid = threadIdx.x >> 6, lane = threadIdx.x & 63;
  int row = blockIdx.x * 4 + wid;
  int idx = (int)indF[row];
  float4 v = *(const float4*)&embed[(size_t)idx * D + lane * 4];
  *(float4*)&outQ[(size_t)row * D + lane * 4] = v;
}

// ---------------------------------------------------------------------------
extern "C" void kernel_launch(void* const* d_in, const int* in_sizes, int n_in,
                              void* d_out, int out_size, void* d_ws, size_t ws_size,
                              hipStream_t stream) {
  const float* x     = (const float*)d_in[0];
  const float* embed = (const float*)d_in[1];
  float* o = (float*)d_out;

  if (ws_size >= WS_NEED) {
    char* w = (char*)d_ws;
    unsigned short* A_h = (unsigned short*)(w + OFF_AH);
    float* x2 = (float*)(w + OFF_X2);
    float* nx = (float*)(w + OFF_NX);
    float* e2 = (float*)(w + OFF_E2);
    unsigned* rowMinU = (unsigned*)(w + OFF_RM);
    unsigned long long* pKey = (unsigned long long*)(w + OFF_PK);
    unsigned* misc = (unsigned*)(w + OFF_MISC);
    unsigned* blkCnt = (unsigned*)(w + OFF_BCNT);
    unsigned* list2 = (unsigned*)(w + OFF_L2);
    uint2* cand = (uint2*)(w + OFF_CAND);

    unsigned short* E_h = (unsigned short*)o;      // 4MB scratch in quantize region
    float* indF = o + QOFF;

    init_kernel<<<128, 256, 0, stream>>>(misc, rowMinU, pKey);
    prep_kernel<<<(NROWS + CODES) / 4, 256, 0, stream>>>(x, embed, A_h, E_h, x2, nx, e2, misc);
    dim3 gridC(NROWS / BM, NSPL);
    gemm_coarse<<<gridC, 256, 0, stream>>>(A_h, E_h, e2, misc, rowMinU,
                                           cand, blkCnt, &misc[1]);
    filter_kernel<<<NBLK, 256, 0, stream>>>(cand, blkCnt, misc, rowMinU, list2);
    refine_kernel<<<1024, 256, 0, stream>>>(x, embed, x2, e2, misc, list2, pKey);
    final_kernel<<<NROWS / 4, 256, 0, stream>>>(embed, pKey, o, indF);
  } else {
    // ---- fp32 fallback ----
    float* x2   = o;
    float* e2   = o + 32768;
    float* pVal = o + 65536;
    int*   pIdx = (int*)(o + 196608);
    float* indF = o + QOFF;
    sq_kernel<<<(NROWS + CODES) / 4, 256, 0, stream>>>(x, embed, x2, e2);
    dim3 gridB(NROWS / BM_F, NSPLIT_F);
    argmin_f32_kernel<<<gridB, 256, 0, stream>>>(x, embed, x2, e2, pVal, pIdx);
    merge_f32_kernel<<<NROWS / 256, 256, 0, stream>>>(pVal, pIdx, indF);
    gather_f32_kernel<<<NROWS / 4, 256, 0, stream>>>(embed, indF, o);
  }
}

// Round 16
// 621.666 us; speedup vs baseline: 1.9021x; 1.7109x over previous
//
#include <hip/hip_runtime.h>
#include <math.h>

#define D       256
#define NROWS   32768      // 8 * 4096
#define CODES   8192
#define QOFF    8388608    // index output offset (floats) in d_out

// ---------------- coarse GEMM config (round-8 engine: fits registers) ------
#define BM      128
#define BN      128
#define NSPL    4
#define SPLC    (CODES / NSPL)    // 2048
#define NCHUNK  (SPLC / BN)       // 16
#define NSTEP   (NCHUNK * 4)      // 64 kb-steps (BK=64)
#define NBLK    1024              // 256 rowTiles * NSPL
#define LQ      1536              // LDS candidate buffer entries (per chunk)
#define SEGQ    3072u             // per-block candidate segment entries (8B)
#define OVCAP   262144u
#define CAP2    1048576u

// rigorous collect margin (2M): 2*2*(2u+u^2)*||x||max*||e||max, u=2^-9 (bf16 rn)
#define MARG_COEF 0.016f
#define MARG_ABS  0.10f

// ---------------- ws layout (bytes) ----------------
#define OFF_AH    0ull               // 16,777,216
#define OFF_X2    16777216ull
#define OFF_NX    16908288ull
#define OFF_E2    17039360ull
#define OFF_RM    17072128ull        // monotone-encoded float bits
#define OFF_PK    17203200ull
#define OFF_MISC  17465344ull        // [1]=ovCnt [2]=neMaxBits [3]=survCnt [4]=nxMaxBits
#define OFF_BCNT  17465600ull
#define OFF_L2    17469696ull        // CAP2 * 4
#define OFF_CAND  21664000ull        // uint2: NBLK*SEGQ segs + OVCAP overflow
#define WS_NEED   48926976ull        // < 51,019,776 proven in round 2

typedef __attribute__((ext_vector_type(8)))  short bf16x8;
typedef __attribute__((ext_vector_type(16))) float f32x16;

__device__ __forceinline__ void gload16(const void* g, void* l) {
  __builtin_amdgcn_global_load_lds(
      (const __attribute__((address_space(1))) unsigned int*)g,
      (__attribute__((address_space(3))) unsigned int*)l, 16, 0, 0);
}

__device__ __forceinline__ unsigned short bf16rn(float x) {
  unsigned u = __float_as_uint(x);
  return (unsigned short)((u + 0x7fffu + ((u >> 16) & 1u)) >> 16);
}

// monotone float <-> uint (order-preserving incl. negatives)
__device__ __forceinline__ unsigned encf(float f) {
  unsigned b = __float_as_uint(f);
  return (b >> 31) ? ~b : (b | 0x80000000u);
}
__device__ __forceinline__ float decf(unsigned u) {
  return __uint_as_float((u >> 31) ? (u ^ 0x80000000u) : ~u);
}

// ---------------------------------------------------------------------------
__global__ __launch_bounds__(256) void init_kernel(unsigned* __restrict__ misc,
                                                   unsigned* __restrict__ rowMinU,
                                                   unsigned long long* __restrict__ pKey) {
  int i = blockIdx.x * 256 + threadIdx.x;   // 32768
  if (i < 16) misc[i] = 0u;
  rowMinU[i] = 0xFFFFFFFFu;
  pKey[i] = ~0ull;
}

// ---------------------------------------------------------------------------
// prep: bf16 h-planes + squared norms.  NO atomics (round-15 lesson: the
// 40960 same-address atomicMax serialized to 469us — G12 violated).
// ---------------------------------------------------------------------------
__global__ __launch_bounds__(256) void prep_kernel(const float* __restrict__ x,
                                                   const float* __restrict__ embed,
                                                   unsigned short* __restrict__ A_h,
                                                   unsigned short* __restrict__ E_h,
                                                   float* __restrict__ x2,
                                                   float* __restrict__ nx,
                                                   float* __restrict__ e2) {
  int wid  = threadIdx.x >> 6;
  int lane = threadIdx.x & 63;
  int rid  = blockIdx.x * 4 + wid;   // 0..40959
  const float* src;
  unsigned short* dst;
  if (rid < NROWS) { src = x + (size_t)rid * D;               dst = A_h + (size_t)rid * D; }
  else             { src = embed + (size_t)(rid - NROWS) * D; dst = E_h + (size_t)(rid - NROWS) * D; }
  float4 v = *(const float4*)(src + lane * 4);
  ushort4 hv = make_ushort4(bf16rn(v.x), bf16rn(v.y), bf16rn(v.z), bf16rn(v.w));
  *(ushort4*)(dst + lane * 4) = hv;
  float p = v.x * v.x + v.y * v.y + v.z * v.z + v.w * v.w;
  #pragma unroll
  for (int off = 32; off > 0; off >>= 1) p += __shfl_down(p, off);
  if (lane == 0) {
    if (rid < NROWS) { x2[rid] = p; nx[rid] = sqrtf(p); }
    else             { e2[rid - NROWS] = p; }
  }
}

// ---------------------------------------------------------------------------
// normmax: max||x|| -> misc[4], max||e|| -> misc[2].  Grid-stride + wave
// reduce + ONE atomicMax per wave (256 atomics total, ~3us).
// ---------------------------------------------------------------------------
__global__ __launch_bounds__(256) void normmax_kernel(const float* __restrict__ nx,
                                                      const float* __restrict__ e2,
                                                      unsigned* __restrict__ misc) {
  int tid = blockIdx.x * 256 + threadIdx.x;
  const int stride = 32 * 256;
  float mx = 0.0f, me = 0.0f;
  for (int i = tid; i < NROWS; i += stride) mx = fmaxf(mx, nx[i]);
  for (int i = tid; i < CODES; i += stride) me = fmaxf(me, e2[i]);
  #pragma unroll
  for (int off = 32; off > 0; off >>= 1) {
    mx = fmaxf(mx, __shfl_down(mx, off));
    me = fmaxf(me, __shfl_down(me, off));
  }
  if ((threadIdx.x & 63) == 0) {
    atomicMax(&misc[4], __float_as_uint(mx));
    atomicMax(&misc[2], __float_as_uint(sqrtf(me)));
  }
}

// ---------------------------------------------------------------------------
// Fused coarse pass on the round-8 engine (128x128 tile, 4 waves 2x2, wave
// tile 64x64 = acc[2][2] -> 64 AGPR + ~100 VGPR: fits the 256-reg budget).
// Per chunk: in-place q transform (acc = e2-2*xe) + running row-min
// (+ l31 butterfly) then collect acc <= runm + rc (global scalar margin)
// into LDS, flushed per chunk to a private per-block segment.
// Superset proof: runm_t >= rowMin_final => anything passing the final
// threshold also passes here; filter reduces to the proven survivor set.
// ---------------------------------------------------------------------------
__global__ __launch_bounds__(256, 2) void gemm_coarse(
    const unsigned short* __restrict__ A_h,
    const unsigned short* __restrict__ E_h,
    const float* __restrict__ e2g,
    const unsigned* __restrict__ miscR,
    unsigned* __restrict__ rowMinU,
    uint2* __restrict__ cand,           // NBLK*SEGQ segments + OVCAP tail
    unsigned* __restrict__ blkCnt,
    unsigned* __restrict__ ovCnt) {     // &misc[1]
  __shared__ __align__(16) char As0[16384];   // 128 rows x 128B (BK=64)
  __shared__ __align__(16) char As1[16384];
  __shared__ __align__(16) char Bs0[16384];
  __shared__ __align__(16) char Bs1[16384];
  __shared__ uint2 lbuf[LQ];                  // 12KB
  __shared__ unsigned lcnt, lnS, lbaseS;

  const int tid  = threadIdx.x;
  const int lane = tid & 63;
  const int wave = tid >> 6;            // 0..3
  const int wm = wave >> 1;             // 0..1  row group (64 rows)
  const int wn = wave & 1;              // 0..1  col group (64 cols)
  const int l31 = lane & 31;
  const int hi16 = (lane >> 5) << 4;
  const int lh4  = (lane >> 5) << 2;
  const int rowBase = blockIdx.x * BM;
  const int split   = blockIdx.y;
  const int seg     = blockIdx.y * 256 + blockIdx.x;

  // per-lane read geometry: frag row&7 == l31&7 for both A and B.
  const int Ccom = hi16 ^ ((l31 & 7) << 4);
  const int Aoff = (wm * 64 + l31) << 7;    // + f*4096 + (Ccom^ks*32)
  const int Boff = (wn * 64 + l31) << 7;    // + g*4096 + (Ccom^ks*32)

  // staging addressing (algebraic form of SWK, 3 registers):
  const int stRB = tid >> 3;                                  // 0..31
  const int stCo = ((tid & 7) << 4) ^ ((stRB & 7) << 4);
  const int stD0 = (tid & ~63) << 4;

  auto STAGE = [&](char* Ad, char* Bd, int s) {
    int cc = s >> 2, kb = s & 3;
    const int cBase = split * SPLC + cc * BN;
    #pragma unroll
    for (int i = 0; i < 4; i++) {
      int row = i * 32 + stRB;
      gload16((const char*)A_h + (((size_t)(rowBase + row)) << 9) + (kb << 7) + stCo,
              Ad + stD0 + i * 4096);
      gload16((const char*)E_h + (((size_t)(cBase + row)) << 9) + (kb << 7) + stCo,
              Bd + stD0 + i * 4096);
    }
  };

  // ---- prologue ----
  if (tid == 0) lcnt = 0;
  const float rc = fmaf(MARG_COEF * __uint_as_float(miscR[4]),
                        __uint_as_float(miscR[2]), MARG_ABS);   // global margin
  float runm[2][16];
  #pragma unroll
  for (int fm = 0; fm < 2; fm++)
    #pragma unroll
    for (int rg = 0; rg < 16; rg++) runm[fm][rg] = INFINITY;
  unsigned segOff = 0;

  STAGE(As0, Bs0, 0);

  f32x16 acc[2][2];
  #pragma unroll
  for (int i = 0; i < 2; i++)
    #pragma unroll
    for (int j = 0; j < 2; j++) acc[i][j] = (f32x16)(0.0f);

  __syncthreads();   // step-0 stage landed

  for (int s = 0; s < NSTEP; ++s) {
    char* Ac = (s & 1) ? As1 : As0;
    char* Bc = (s & 1) ? Bs1 : Bs0;
    if (s + 1 < NSTEP) STAGE((s & 1) ? As0 : As1, (s & 1) ? Bs0 : Bs1, s + 1);

    #pragma unroll
    for (int ks = 0; ks < 4; ++ks) {
      const int off = Ccom ^ (ks << 5);
      bf16x8 a0 = *(const bf16x8*)(Ac + Aoff + off);
      bf16x8 a1 = *(const bf16x8*)(Ac + Aoff + 4096 + off);
      bf16x8 b0 = *(const bf16x8*)(Bc + Boff + off);
      bf16x8 b1 = *(const bf16x8*)(Bc + Boff + 4096 + off);
      acc[0][0] = __builtin_amdgcn_mfma_f32_32x32x16_bf16(a0, b0, acc[0][0], 0, 0, 0);
      acc[1][0] = __builtin_amdgcn_mfma_f32_32x32x16_bf16(a1, b0, acc[1][0], 0, 0, 0);
      acc[0][1] = __builtin_amdgcn_mfma_f32_32x32x16_bf16(a0, b1, acc[0][1], 0, 0, 0);
      acc[1][1] = __builtin_amdgcn_mfma_f32_32x32x16_bf16(a1, b1, acc[1][1], 0, 0, 0);
    }

    if ((s & 3) == 3) {
      const int cc = s >> 2;
      const int cBase = split * SPLC + cc * BN;

      // in-place q transform + running min
      #pragma unroll
      for (int g = 0; g < 2; g++) {
        float e2c = e2g[cBase + wn * 64 + g * 32 + l31];
        #pragma unroll
        for (int fm = 0; fm < 2; fm++)
          #pragma unroll
          for (int rg = 0; rg < 16; rg++) {
            float qv = fmaf(acc[fm][g][rg], -2.0f, e2c);
            acc[fm][g][rg] = qv;
            runm[fm][rg] = fminf(runm[fm][rg], qv);
          }
      }
      // butterfly over the 32 col-lanes -> lane-uniform row min (so far)
      #pragma unroll
      for (int fm = 0; fm < 2; fm++)
        #pragma unroll
        for (int rg = 0; rg < 16; rg++) {
          float v = runm[fm][rg];
          #pragma unroll
          for (int off = 1; off < 32; off <<= 1) v = fminf(v, __shfl_xor(v, off));
          runm[fm][rg] = v;
        }
      // collect with the fresh threshold
      #pragma unroll
      for (int g = 0; g < 2; g++) {
        int col = cBase + wn * 64 + g * 32 + l31;
        #pragma unroll
        for (int fm = 0; fm < 2; fm++)
          #pragma unroll
          for (int rg = 0; rg < 16; rg++) {
            float qv = acc[fm][g][rg];
            if (qv <= runm[fm][rg] + rc) {
              int row = rowBase + wm * 64 + fm * 32 + ((rg & 3) + 8 * (rg >> 2)) + lh4;
              uint2 en = make_uint2((unsigned)((row << 13) | col), __float_as_uint(qv));
              unsigned p = atomicAdd(&lcnt, 1u);
              if (p < LQ) lbuf[p] = en;
              else { unsigned gp = atomicAdd(ovCnt, 1u);
                     if (gp < OVCAP) cand[(size_t)NBLK * SEGQ + gp] = en; }
            }
          }
      }
      #pragma unroll
      for (int i = 0; i < 2; i++)
        #pragma unroll
        for (int j = 0; j < 2; j++) acc[i][j] = (f32x16)(0.0f);
    }

    __syncthreads();   // drains next-step stage; all appends of this chunk done

    if ((s & 3) == 3) {
      // flush lbuf -> private segment (no global counter contention)
      if (tid == 0) {
        unsigned n = lcnt; if (n > LQ) n = LQ;
        lnS = n; lbaseS = segOff; segOff += n; lcnt = 0;
      }
      __syncthreads();
      unsigned n = lnS, base = lbaseS;
      for (unsigned i = tid; i < n; i += 256) {
        unsigned gp = base + i;
        if (gp < SEGQ) cand[(size_t)seg * SEGQ + gp] = lbuf[i];
        else { unsigned op = atomicAdd(ovCnt, 1u);
               if (op < OVCAP) cand[(size_t)NBLK * SEGQ + op] = lbuf[i]; }
      }
      // copies finish before next chunk's appends (>=4 step barriers away)
    }
  }

  // final per-row min (runm lane-uniform after last chunk's butterfly)
  if (l31 == 0) {
    #pragma unroll
    for (int fm = 0; fm < 2; fm++)
      #pragma unroll
      for (int rg = 0; rg < 16; rg++) {
        int row = rowBase + wm * 64 + fm * 32 + ((rg & 3) + 8 * (rg >> 2)) + lh4;
        atomicMin(&rowMinU[row], encf(runm[fm][rg]));
      }
  }
  if (tid == 0) blkCnt[seg] = (segOff > SEGQ) ? SEGQ : segOff;
}

// ---------------------------------------------------------------------------
// filter: re-test stored coarse q against FINAL rowMin + global margin.
// ---------------------------------------------------------------------------
__global__ __launch_bounds__(256) void filter_kernel(const uint2* __restrict__ cand,
                                                     const unsigned* __restrict__ blkCnt,
                                                     unsigned* __restrict__ misc,
                                                     const unsigned* __restrict__ rowMinU,
                                                     unsigned* __restrict__ list2) {
  const float rc = fmaf(MARG_COEF * __uint_as_float(misc[4]),
                        __uint_as_float(misc[2]), MARG_ABS);
  auto test = [&](uint2 en) {
    unsigned row = en.x >> 13;
    float q  = __uint_as_float(en.y);
    float rm = decf(rowMinU[row]);
    if (q <= rm + rc) {
      unsigned p = atomicAdd(&misc[3], 1u);
      if (p < CAP2) list2[p] = en.x;
    }
  };
  unsigned seg = blockIdx.x;               // NBLK blocks
  unsigned n = blkCnt[seg]; if (n > SEGQ) n = SEGQ;
  const uint2* sp = cand + (size_t)seg * SEGQ;
  for (unsigned i = threadIdx.x; i < n; i += 256) test(sp[i]);

  unsigned ov = misc[1]; if (ov > OVCAP) ov = OVCAP;
  const uint2* op = cand + (size_t)NBLK * SEGQ;
  for (unsigned i = blockIdx.x * 256 + threadIdx.x; i < ov; i += NBLK * 256) test(op[i]);
}

// ---------------------------------------------------------------------------
// refine: 16-lane groups, fp64 dot, exact ref combine, u64 atomicMin key.
// ---------------------------------------------------------------------------
__global__ __launch_bounds__(256) void refine_kernel(const float* __restrict__ x,
                                                     const float* __restrict__ embed,
                                                     const float* __restrict__ x2g,
                                                     const float* __restrict__ e2g,
                                                     const unsigned* __restrict__ miscR,
                                                     const unsigned* __restrict__ list2,
                                                     unsigned long long* __restrict__ pKey) {
  const int l16 = threadIdx.x & 15;
  unsigned total = miscR[3]; if (total > CAP2) total = CAP2;
  unsigned gid = (blockIdx.x * 256 + threadIdx.x) >> 4;
  unsigned ng  = (gridDim.x * 256) >> 4;
  for (unsigned i = gid; i < total; i += ng) {
    unsigned pk = list2[i];
    int row = (int)(pk >> 13), col = (int)(pk & 8191u);
    double s = 0.0;
    #pragma unroll
    for (int p = 0; p < 4; p++) {
      float4 xv = *(const float4*)&x[(size_t)row * D + p * 64 + l16 * 4];
      float4 ev = *(const float4*)&embed[(size_t)col * D + p * 64 + l16 * 4];
      s = fma((double)xv.x, (double)ev.x, s);
      s = fma((double)xv.y, (double)ev.y, s);
      s = fma((double)xv.z, (double)ev.z, s);
      s = fma((double)xv.w, (double)ev.w, s);
    }
    #pragma unroll
    for (int off = 1; off < 16; off <<= 1) s += __shfl_xor(s, off);
    if (l16 == 0) {
      float xef = (float)s;
      float ss  = __fadd_rn(x2g[row], e2g[col]);
      float d2  = __fsub_rn(ss, __fmul_rn(2.0f, xef));
      d2 = fmaxf(d2, 0.0f);
      float sq = sqrtf(d2);
      unsigned long long key =
          ((unsigned long long)__float_as_uint(sq) << 32) | (unsigned)col;
      atomicMin(pKey + row, key);
    }
  }
}

// ---------------------------------------------------------------------------
// finalize: gather codes + write index as float.
// ---------------------------------------------------------------------------
__global__ __launch_bounds__(256) void final_kernel(const float* __restrict__ embed,
                                                    const unsigned long long* __restrict__ pKey,
                                                    float* __restrict__ outQ,
                                                    float* __restrict__ indF) {
  int wid  = threadIdx.x >> 6;
  int lane = threadIdx.x & 63;
  int row  = blockIdx.x * 4 + wid;
  unsigned long long k = pKey[row];
  int idx = (int)(k & 8191ull);
  float4 v = *(const float4*)&embed[(size_t)idx * D + lane * 4];
  *(float4*)&outQ[(size_t)row * D + lane * 4] = v;
  if (lane == 0) indF[row] = (float)idx;
}

// ===========================================================================
// Fallback fp32 path (round-1, proven) — used if ws_size < WS_NEED.
// ===========================================================================
#define BM_F 128
#define BN_F 128
#define BK_F 32
#define NSPLIT_F 4
#define SPLIT_CF (CODES / NSPLIT_F)

__global__ __launch_bounds__(256) void sq_kernel(const float* __restrict__ x,
                                                 const float* __restrict__ embed,
                                                 float* __restrict__ x2,
                                                 float* __restrict__ e2) {
  int wid  = threadIdx.x >> 6;
  int lane = threadIdx.x & 63;
  int rid  = blockIdx.x * 4 + wid;
  const float* base = (rid < NROWS) ? (x + (size_t)rid * D)
                                    : (embed + (size_t)(rid - NROWS) * D);
  float4 v = *(const float4*)(base + lane * 4);
  float p = v.x * v.x + v.y * v.y + v.z * v.z + v.w * v.w;
  #pragma unroll
  for (int off = 32; off > 0; off >>= 1) p += __shfl_down(p, off);
  if (lane == 0) {
    if (rid < NROWS) x2[rid] = p;
    else             e2[rid - NROWS] = p;
  }
}

__global__ __launch_bounds__(256) void argmin_f32_kernel(const float* __restrict__ x,
                                                         const float* __restrict__ embed,
                                                         const float* __restrict__ x2,
                                                         const float* __restrict__ e2,
                                                         float* __restrict__ pVal,
                                                         int* __restrict__ pIdx) {
  __shared__ float As[BK_F][BM_F];
  __shared__ float Bs[BK_F][BN_F];
  const int tid = threadIdx.x;
  const int ty = tid >> 4, tx = tid & 15;
  const int rowBase = blockIdx.x * BM_F;
  const int split = blockIdx.y;
  const int r0 = ty * 8, c0 = tx * 8;
  float bestV[8]; int bestI[8];
  #pragma unroll
  for (int i = 0; i < 8; i++) { bestV[i] = -INFINITY; bestI[i] = 0; }
  float x2r[8];
  #pragma unroll
  for (int i = 0; i < 8; i++) x2r[i] = x2[rowBase + r0 + i];
  for (int chunk = 0; chunk < SPLIT_CF / BN_F; ++chunk) {
    const int cBase = split * SPLIT_CF + chunk * BN_F;
    float acc[8][8];
    #pragma unroll
    for (int i = 0; i < 8; i++)
      #pragma unroll
      for (int j = 0; j < 8; j++) acc[i][j] = 0.0f;
    for (int kb = 0; kb < D / BK_F; ++kb) {
      #pragma unroll
      for (int i = 0; i < 4; i++) {
        int f4 = tid + i * 256;
        int rr = f4 >> 3, k4 = f4 & 7;
        float4 va = *(const float4*)&x[(size_t)(rowBase + rr) * D + kb * BK_F + k4 * 4];
        As[k4 * 4 + 0][rr] = va.x; As[k4 * 4 + 1][rr] = va.y;
        As[k4 * 4 + 2][rr] = va.z; As[k4 * 4 + 3][rr] = va.w;
        float4 vb = *(const float4*)&embed[(size_t)(cBase + rr) * D + kb * BK_F + k4 * 4];
        Bs[k4 * 4 + 0][rr] = vb.x; Bs[k4 * 4 + 1][rr] = vb.y;
        Bs[k4 * 4 + 2][rr] = vb.z; Bs[k4 * 4 + 3][rr] = vb.w;
      }
      __syncthreads();
      #pragma unroll 8
      for (int kk = 0; kk < BK_F; kk++) {
        float a[8], b[8];
        *(float4*)&a[0] = *(const float4*)&As[kk][r0];
        *(float4*)&a[4] = *(const float4*)&As[kk][r0 + 4];
        *(float4*)&b[0] = *(const float4*)&Bs[kk][c0];
        *(float4*)&b[4] = *(const float4*)&Bs[kk][c0 + 4];
        #pragma unroll
        for (int i = 0; i < 8; i++)
          #pragma unroll
          for (int j = 0; j < 8; j++)
            acc[i][j] = fmaf(a[i], b[j], acc[i][j]);
      }
      __syncthreads();
    }
    #pragma unroll
    for (int j = 0; j < 8; j++) {
      int c = cBase + c0 + j;
      float e2c = e2[c];
      #pragma unroll
      for (int i = 0; i < 8; i++) {
        float s  = __fadd_rn(x2r[i], e2c);
        float u  = __fmul_rn(2.0f, acc[i][j]);
        float d2 = fmaxf(__fsub_rn(s, u), 0.0f);
        float dist = -sqrtf(d2);
        if (dist > bestV[i]) { bestV[i] = dist; bestI[i] = c; }
      }
    }
  }
  __syncthreads();
  float* Vl = &As[0][0];
  int*   Il = (int*)&Bs[0][0];
  #pragma unroll
  for (int i = 0; i < 8; i++) {
    Vl[(ty * 16 + tx) * 8 + i] = bestV[i];
    Il[(ty * 16 + tx) * 8 + i] = bestI[i];
  }
  __syncthreads();
  if (tid < BM_F) {
    int rr = tid, tyr = rr >> 3, ii = rr & 7;
    float bv = -INFINITY; int bi = 0;
    #pragma unroll
    for (int t = 0; t < 16; t++) {
      float v = Vl[(tyr * 16 + t) * 8 + ii];
      int  iv = Il[(tyr * 16 + t) * 8 + ii];
      if (v > bv || (v == bv && iv < bi)) { bv = v; bi = iv; }
    }
    pVal[split * NROWS + rowBase + rr] = bv;
    pIdx[split * NROWS + rowBase + rr] = bi;
  }
}

__global__ __launch_bounds__(256) void merge_f32_kernel(const float* __restrict__ pVal,
                                                        const int* __restrict__ pIdx,
                                                        float* __restrict__ indF) {
  int row = blockIdx.x * 256 + threadIdx.x;
  if (row >= NROWS) return;
  float bv = -INFINITY; int bi = 0;
  #pragma unroll
  for (int s = 0; s < NSPLIT_F; s++) {
    float v = pVal[s * NROWS + row];
    int  iv = pIdx[s * NROWS + row];
    if (v > bv || (v == bv && iv < bi)) { bv = v; bi = iv; }
  }
  indF[row] = (float)bi;
}

__global__ __launch_bounds__(256) void gather_f32_kernel(const float* __restrict__ embed,
                                                         const float* __restrict__ indF,
                                                         float* __restrict__ outQ) {
  int wid = threadIdx.x >> 6, lane = threadIdx.x & 63;
  int row = blockIdx.x * 4 + wid;
  int idx = (int)indF[row];
  float4 v = *(const float4*)&embed[(size_t)idx * D + lane * 4];
  *(float4*)&outQ[(size_t)row * D + lane * 4] = v;
}

// ---------------------------------------------------------------------------
extern "C" void kernel_launch(void* const* d_in, const int* in_sizes, int n_in,
                              void* d_out, int out_size, void* d_ws, size_t ws_size,
                              hipStream_t stream) {
  const float* x     = (const float*)d_in[0];
  const float* embed = (const float*)d_in[1];
  float* o = (float*)d_out;

  if (ws_size >= WS_NEED) {
    char* w = (char*)d_ws;
    unsigned short* A_h = (unsigned short*)(w + OFF_AH);
    float* x2 = (float*)(w + OFF_X2);
    float* nx = (float*)(w + OFF_NX);
    float* e2 = (float*)(w + OFF_E2);
    unsigned* rowMinU = (unsigned*)(w + OFF_RM);
    unsigned long long* pKey = (unsigned long long*)(w + OFF_PK);
    unsigned* misc = (unsigned*)(w + OFF_MISC);
    unsigned* blkCnt = (unsigned*)(w + OFF_BCNT);
    unsigned* list2 = (unsigned*)(w + OFF_L2);
    uint2* cand = (uint2*)(w + OFF_CAND);

    unsigned short* E_h = (unsigned short*)o;      // 4MB scratch in quantize region
    float* indF = o + QOFF;

    init_kernel<<<128, 256, 0, stream>>>(misc, rowMinU, pKey);
    prep_kernel<<<(NROWS + CODES) / 4, 256, 0, stream>>>(x, embed, A_h, E_h, x2, nx, e2);
    normmax_kernel<<<32, 256, 0, stream>>>(nx, e2, misc);
    dim3 gridC(NROWS / BM, NSPL);
    gemm_coarse<<<gridC, 256, 0, stream>>>(A_h, E_h, e2, misc, rowMinU,
                                           cand, blkCnt, &misc[1]);
    filter_kernel<<<NBLK, 256, 0, stream>>>(cand, blkCnt, misc, rowMinU, list2);
    refine_kernel<<<1024, 256, 0, stream>>>(x, embed, x2, e2, misc, list2, pKey);
    final_kernel<<<NROWS / 4, 256, 0, stream>>>(embed, pKey, o, indF);
  } else {
    // ---- fp32 fallback ----
    float* x2   = o;
    float* e2   = o + 32768;
    float* pVal = o + 65536;
    int*   pIdx = (int*)(o + 196608);
    float* indF = o + QOFF;
    sq_kernel<<<(NROWS + CODES) / 4, 256, 0, stream>>>(x, embed, x2, e2);
    dim3 gridB(NROWS / BM_F, NSPLIT_F);
    argmin_f32_kernel<<<gridB, 256, 0, stream>>>(x, embed, x2, e2, pVal, pIdx);
    merge_f32_kernel<<<NROWS / 256, 256, 0, stream>>>(pVal, pIdx, indF);
    gather_f32_kernel<<<NROWS / 4, 256, 0, stream>>>(embed, indF, o);
  }
}

// Round 17
// 477.072 us; speedup vs baseline: 2.4786x; 1.3031x over previous
//
#include <hip/hip_runtime.h>
#include <math.h>

#define D       256
#define NROWS   32768      // 8 * 4096
#define CODES   8192
#define QOFF    8388608    // index output offset (floats) in d_out

// ---------------- coarse GEMM config (round-8 engine: fits registers) ------
#define BM      128
#define BN      128
#define NSPL    2
#define SPLC    (CODES / NSPL)    // 4096
#define NCHUNK  (SPLC / BN)       // 32
#define NSTEP   (NCHUNK * 4)      // 128 kb-steps (BK=64)
#define NBLK    512               // 256 rowTiles * NSPL
#define LQ      1536              // LDS candidate buffer entries (per 4 chunks)
#define SEGQ    6144u             // per-block candidate segment entries (8B)
#define OVCAP   262144u
#define CAP2    1048576u

// rigorous collect margin (2M): 2*2*(2u+u^2)*||x||*||e||max, u=2^-9 (bf16 rn)
#define MARG_COEF 0.016f
#define MARG_ABS  0.10f

// ---------------- ws layout (bytes) ----------------
#define OFF_AH    0ull               // 16,777,216
#define OFF_X2    16777216ull
#define OFF_NX    16908288ull
#define OFF_E2    17039360ull
#define OFF_RM    17072128ull        // monotone-encoded float bits
#define OFF_PK    17203200ull
#define OFF_MISC  17465344ull        // [1]=ovCnt [2]=neMaxBits [3]=survCnt [4]=nxMaxBits
#define OFF_BCNT  17465600ull
#define OFF_L2    17469696ull        // CAP2 * 4
#define OFF_CAND  21664000ull        // uint2: NBLK*SEGQ segs + OVCAP overflow
#define WS_NEED   48926976ull        // < 51,019,776 proven in round 2

typedef __attribute__((ext_vector_type(8)))  short bf16x8;
typedef __attribute__((ext_vector_type(16))) float f32x16;

__device__ __forceinline__ void gload16(const void* g, void* l) {
  __builtin_amdgcn_global_load_lds(
      (const __attribute__((address_space(1))) unsigned int*)g,
      (__attribute__((address_space(3))) unsigned int*)l, 16, 0, 0);
}

__device__ __forceinline__ unsigned short bf16rn(float x) {
  unsigned u = __float_as_uint(x);
  return (unsigned short)((u + 0x7fffu + ((u >> 16) & 1u)) >> 16);
}

// monotone float <-> uint (order-preserving incl. negatives)
__device__ __forceinline__ unsigned encf(float f) {
  unsigned b = __float_as_uint(f);
  return (b >> 31) ? ~b : (b | 0x80000000u);
}
__device__ __forceinline__ float decf(unsigned u) {
  return __uint_as_float((u >> 31) ? (u ^ 0x80000000u) : ~u);
}

// ---------------------------------------------------------------------------
__global__ __launch_bounds__(256) void init_kernel(unsigned* __restrict__ misc,
                                                   unsigned* __restrict__ rowMinU,
                                                   unsigned long long* __restrict__ pKey) {
  int i = blockIdx.x * 256 + threadIdx.x;   // 32768
  if (i < 16) misc[i] = 0u;
  rowMinU[i] = 0xFFFFFFFFu;
  pKey[i] = ~0ull;
}

// ---------------------------------------------------------------------------
// prep: bf16 h-planes + squared norms.  NO atomics (round-15 lesson).
// ---------------------------------------------------------------------------
__global__ __launch_bounds__(256) void prep_kernel(const float* __restrict__ x,
                                                   const float* __restrict__ embed,
                                                   unsigned short* __restrict__ A_h,
                                                   unsigned short* __restrict__ E_h,
                                                   float* __restrict__ x2,
                                                   float* __restrict__ nx,
                                                   float* __restrict__ e2) {
  int wid  = threadIdx.x >> 6;
  int lane = threadIdx.x & 63;
  int rid  = blockIdx.x * 4 + wid;   // 0..40959
  const float* src;
  unsigned short* dst;
  if (rid < NROWS) { src = x + (size_t)rid * D;               dst = A_h + (size_t)rid * D; }
  else             { src = embed + (size_t)(rid - NROWS) * D; dst = E_h + (size_t)(rid - NROWS) * D; }
  float4 v = *(const float4*)(src + lane * 4);
  ushort4 hv = make_ushort4(bf16rn(v.x), bf16rn(v.y), bf16rn(v.z), bf16rn(v.w));
  *(ushort4*)(dst + lane * 4) = hv;
  float p = v.x * v.x + v.y * v.y + v.z * v.z + v.w * v.w;
  #pragma unroll
  for (int off = 32; off > 0; off >>= 1) p += __shfl_down(p, off);
  if (lane == 0) {
    if (rid < NROWS) { x2[rid] = p; nx[rid] = sqrtf(p); }
    else             { e2[rid - NROWS] = p; }
  }
}

// ---------------------------------------------------------------------------
// normmax: max||x|| -> misc[4], max||e|| -> misc[2].  One atomic per wave.
// ---------------------------------------------------------------------------
__global__ __launch_bounds__(256) void normmax_kernel(const float* __restrict__ nx,
                                                      const float* __restrict__ e2,
                                                      unsigned* __restrict__ misc) {
  int tid = blockIdx.x * 256 + threadIdx.x;
  const int stride = 32 * 256;
  float mx = 0.0f, me = 0.0f;
  for (int i = tid; i < NROWS; i += stride) mx = fmaxf(mx, nx[i]);
  for (int i = tid; i < CODES; i += stride) me = fmaxf(me, e2[i]);
  #pragma unroll
  for (int off = 32; off > 0; off >>= 1) {
    mx = fmaxf(mx, __shfl_down(mx, off));
    me = fmaxf(me, __shfl_down(me, off));
  }
  if ((threadIdx.x & 63) == 0) {
    atomicMax(&misc[4], __float_as_uint(mx));
    atomicMax(&misc[2], __float_as_uint(sqrtf(me)));
  }
}

// ---------------------------------------------------------------------------
// Fused coarse pass, thin epilogue: per chunk only {in-place q transform +
// per-lane running min + single collect sweep vs a STALE uniform threshold}.
// Butterfly (l31 reduce) + threshold refresh + LDS flush only at chunks
// {0, 3, 7, ..., 31} — 9 butterflies / 8 flushes instead of 32/32.
// Staleness is safe: thr = runm_butterflied + rc >= rowMin_final + rc, so
// every candidate within the final margin is still collected (superset);
// the filter prunes the extras.  Chunk 31 is butterflied => final atomicMin
// uses the exact per-split row min.
// ---------------------------------------------------------------------------
__global__ __launch_bounds__(256, 2) void gemm_coarse(
    const unsigned short* __restrict__ A_h,
    const unsigned short* __restrict__ E_h,
    const float* __restrict__ e2g,
    const unsigned* __restrict__ miscR,
    unsigned* __restrict__ rowMinU,
    uint2* __restrict__ cand,           // NBLK*SEGQ segments + OVCAP tail
    unsigned* __restrict__ blkCnt,
    unsigned* __restrict__ ovCnt) {     // &misc[1]
  __shared__ __align__(16) char As0[16384];   // 128 rows x 128B (BK=64)
  __shared__ __align__(16) char As1[16384];
  __shared__ __align__(16) char Bs0[16384];
  __shared__ __align__(16) char Bs1[16384];
  __shared__ uint2 lbuf[LQ];                  // 12KB
  __shared__ unsigned lcnt, lnS, lbaseS;

  const int tid  = threadIdx.x;
  const int lane = tid & 63;
  const int wave = tid >> 6;            // 0..3
  const int wm = wave >> 1;             // 0..1  row group (64 rows)
  const int wn = wave & 1;              // 0..1  col group (64 cols)
  const int l31 = lane & 31;
  const int hi16 = (lane >> 5) << 4;
  const int lh4  = (lane >> 5) << 2;
  const int rowBase = blockIdx.x * BM;
  const int split   = blockIdx.y;
  const int seg     = blockIdx.y * 256 + blockIdx.x;

  // per-lane read geometry: frag row&7 == l31&7 for both A and B.
  const int Ccom = hi16 ^ ((l31 & 7) << 4);
  const int Aoff = (wm * 64 + l31) << 7;    // + f*4096 + (Ccom^ks*32)
  const int Boff = (wn * 64 + l31) << 7;    // + g*4096 + (Ccom^ks*32)

  // staging addressing (algebraic form of SWK, 3 registers):
  const int stRB = tid >> 3;                                  // 0..31
  const int stCo = ((tid & 7) << 4) ^ ((stRB & 7) << 4);
  const int stD0 = (tid & ~63) << 4;

  auto STAGE = [&](char* Ad, char* Bd, int s) {
    int cc = s >> 2, kb = s & 3;
    const int cBase = split * SPLC + cc * BN;
    #pragma unroll
    for (int i = 0; i < 4; i++) {
      int row = i * 32 + stRB;
      gload16((const char*)A_h + (((size_t)(rowBase + row)) << 9) + (kb << 7) + stCo,
              Ad + stD0 + i * 4096);
      gload16((const char*)E_h + (((size_t)(cBase + row)) << 9) + (kb << 7) + stCo,
              Bd + stD0 + i * 4096);
    }
  };

  // ---- prologue ----
  if (tid == 0) lcnt = 0;
  const float rc = fmaf(MARG_COEF * __uint_as_float(miscR[4]),
                        __uint_as_float(miscR[2]), MARG_ABS);   // global margin
  float runm[2][16], thr[2][16];
  #pragma unroll
  for (int fm = 0; fm < 2; fm++)
    #pragma unroll
    for (int rg = 0; rg < 16; rg++) { runm[fm][rg] = INFINITY; thr[fm][rg] = INFINITY; }
  unsigned segOff = 0;

  STAGE(As0, Bs0, 0);

  f32x16 acc[2][2];
  #pragma unroll
  for (int i = 0; i < 2; i++)
    #pragma unroll
    for (int j = 0; j < 2; j++) acc[i][j] = (f32x16)(0.0f);

  __syncthreads();   // step-0 stage landed

  for (int s = 0; s < NSTEP; ++s) {
    char* Ac = (s & 1) ? As1 : As0;
    char* Bc = (s & 1) ? Bs1 : Bs0;
    if (s + 1 < NSTEP) STAGE((s & 1) ? As0 : As1, (s & 1) ? Bs0 : Bs1, s + 1);

    #pragma unroll
    for (int ks = 0; ks < 4; ++ks) {
      const int off = Ccom ^ (ks << 5);
      bf16x8 a0 = *(const bf16x8*)(Ac + Aoff + off);
      bf16x8 a1 = *(const bf16x8*)(Ac + Aoff + 4096 + off);
      bf16x8 b0 = *(const bf16x8*)(Bc + Boff + off);
      bf16x8 b1 = *(const bf16x8*)(Bc + Boff + 4096 + off);
      acc[0][0] = __builtin_amdgcn_mfma_f32_32x32x16_bf16(a0, b0, acc[0][0], 0, 0, 0);
      acc[1][0] = __builtin_amdgcn_mfma_f32_32x32x16_bf16(a1, b0, acc[1][0], 0, 0, 0);
      acc[0][1] = __builtin_amdgcn_mfma_f32_32x32x16_bf16(a0, b1, acc[0][1], 0, 0, 0);
      acc[1][1] = __builtin_amdgcn_mfma_f32_32x32x16_bf16(a1, b1, acc[1][1], 0, 0, 0);
    }

    if ((s & 3) == 3) {
      const int cc = s >> 2;
      const int cBase = split * SPLC + cc * BN;
      const bool doRed = (cc == 0) || ((cc & 3) == 3);

      // in-place q transform + per-lane running min (single sweep)
      #pragma unroll
      for (int g = 0; g < 2; g++) {
        float e2c = e2g[cBase + wn * 64 + g * 32 + l31];
        #pragma unroll
        for (int fm = 0; fm < 2; fm++)
          #pragma unroll
          for (int rg = 0; rg < 16; rg++) {
            float qv = fmaf(acc[fm][g][rg], -2.0f, e2c);
            acc[fm][g][rg] = qv;
            runm[fm][rg] = fminf(runm[fm][rg], qv);
          }
      }
      // butterfly + threshold refresh only on reduction chunks
      if (doRed) {
        #pragma unroll
        for (int fm = 0; fm < 2; fm++)
          #pragma unroll
          for (int rg = 0; rg < 16; rg++) {
            float v = runm[fm][rg];
            #pragma unroll
            for (int off = 1; off < 32; off <<= 1) v = fminf(v, __shfl_xor(v, off));
            runm[fm][rg] = v;
            thr[fm][rg]  = v + rc;
          }
      }
      // collect vs (possibly stale) uniform threshold
      #pragma unroll
      for (int g = 0; g < 2; g++) {
        int col = cBase + wn * 64 + g * 32 + l31;
        #pragma unroll
        for (int fm = 0; fm < 2; fm++)
          #pragma unroll
          for (int rg = 0; rg < 16; rg++) {
            float qv = acc[fm][g][rg];
            if (qv <= thr[fm][rg]) {
              int row = rowBase + wm * 64 + fm * 32 + ((rg & 3) + 8 * (rg >> 2)) + lh4;
              uint2 en = make_uint2((unsigned)((row << 13) | col), __float_as_uint(qv));
              unsigned p = atomicAdd(&lcnt, 1u);
              if (p < LQ) lbuf[p] = en;
              else { unsigned gp = atomicAdd(ovCnt, 1u);
                     if (gp < OVCAP) cand[(size_t)NBLK * SEGQ + gp] = en; }
            }
          }
      }
      #pragma unroll
      for (int i = 0; i < 2; i++)
        #pragma unroll
        for (int j = 0; j < 2; j++) acc[i][j] = (f32x16)(0.0f);
    }

    __syncthreads();   // drains next-step stage; appends of this chunk done

    if ((s & 3) == 3 && (((s >> 2) & 3) == 3)) {
      // flush lbuf -> private segment once per 4 chunks
      if (tid == 0) {
        unsigned n = lcnt; if (n > LQ) n = LQ;
        lnS = n; lbaseS = segOff; segOff += n; lcnt = 0;
      }
      __syncthreads();
      unsigned n = lnS, base = lbaseS;
      for (unsigned i = tid; i < n; i += 256) {
        unsigned gp = base + i;
        if (gp < SEGQ) cand[(size_t)seg * SEGQ + gp] = lbuf[i];
        else { unsigned op = atomicAdd(ovCnt, 1u);
               if (op < OVCAP) cand[(size_t)NBLK * SEGQ + op] = lbuf[i]; }
      }
      // copies finish before next chunk's appends (>=4 step barriers away)
    }
  }

  // final per-row min (chunk 31 was butterflied -> runm lane-uniform)
  if (l31 == 0) {
    #pragma unroll
    for (int fm = 0; fm < 2; fm++)
      #pragma unroll
      for (int rg = 0; rg < 16; rg++) {
        int row = rowBase + wm * 64 + fm * 32 + ((rg & 3) + 8 * (rg >> 2)) + lh4;
        atomicMin(&rowMinU[row], encf(runm[fm][rg]));
      }
  }
  if (tid == 0) blkCnt[seg] = (segOff > SEGQ) ? SEGQ : segOff;
}

// ---------------------------------------------------------------------------
// filter: re-test stored coarse q against FINAL rowMin with PER-ROW margin
// (tighter than the collect's global margin -> fewer fp64 refinements).
// ---------------------------------------------------------------------------
__global__ __launch_bounds__(256) void filter_kernel(const uint2* __restrict__ cand,
                                                     const unsigned* __restrict__ blkCnt,
                                                     unsigned* __restrict__ misc,
                                                     const unsigned* __restrict__ rowMinU,
                                                     const float* __restrict__ nxg,
                                                     unsigned* __restrict__ list2) {
  const float neMaxF = __uint_as_float(misc[2]);
  auto test = [&](uint2 en) {
    unsigned row = en.x >> 13;
    float q  = __uint_as_float(en.y);
    float rm = decf(rowMinU[row]);
    float rcr = fmaf(MARG_COEF * nxg[row], neMaxF, MARG_ABS);
    if (q <= rm + rcr) {
      unsigned p = atomicAdd(&misc[3], 1u);
      if (p < CAP2) list2[p] = en.x;
    }
  };
  unsigned seg = blockIdx.x;               // NBLK blocks
  unsigned n = blkCnt[seg]; if (n > SEGQ) n = SEGQ;
  const uint2* sp = cand + (size_t)seg * SEGQ;
  for (unsigned i = threadIdx.x; i < n; i += 256) test(sp[i]);

  unsigned ov = misc[1]; if (ov > OVCAP) ov = OVCAP;
  const uint2* op = cand + (size_t)NBLK * SEGQ;
  for (unsigned i = blockIdx.x * 256 + threadIdx.x; i < ov; i += NBLK * 256) test(op[i]);
}

// ---------------------------------------------------------------------------
// refine: 16-lane groups, fp64 dot, exact ref combine, u64 atomicMin key.
// ---------------------------------------------------------------------------
__global__ __launch_bounds__(256) void refine_kernel(const float* __restrict__ x,
                                                     const float* __restrict__ embed,
                                                     const float* __restrict__ x2g,
                                                     const float* __restrict__ e2g,
                                                     const unsigned* __restrict__ miscR,
                                                     const unsigned* __restrict__ list2,
                                                     unsigned long long* __restrict__ pKey) {
  const int l16 = threadIdx.x & 15;
  unsigned total = miscR[3]; if (total > CAP2) total = CAP2;
  unsigned gid = (blockIdx.x * 256 + threadIdx.x) >> 4;
  unsigned ng  = (gridDim.x * 256) >> 4;
  for (unsigned i = gid; i < total; i += ng) {
    unsigned pk = list2[i];
    int row = (int)(pk >> 13), col = (int)(pk & 8191u);
    double s = 0.0;
    #pragma unroll
    for (int p = 0; p < 4; p++) {
      float4 xv = *(const float4*)&x[(size_t)row * D + p * 64 + l16 * 4];
      float4 ev = *(const float4*)&embed[(size_t)col * D + p * 64 + l16 * 4];
      s = fma((double)xv.x, (double)ev.x, s);
      s = fma((double)xv.y, (double)ev.y, s);
      s = fma((double)xv.z, (double)ev.z, s);
      s = fma((double)xv.w, (double)ev.w, s);
    }
    #pragma unroll
    for (int off = 1; off < 16; off <<= 1) s += __shfl_xor(s, off);
    if (l16 == 0) {
      float xef = (float)s;
      float ss  = __fadd_rn(x2g[row], e2g[col]);
      float d2  = __fsub_rn(ss, __fmul_rn(2.0f, xef));
      d2 = fmaxf(d2, 0.0f);
      float sq = sqrtf(d2);
      unsigned long long key =
          ((unsigned long long)__float_as_uint(sq) << 32) | (unsigned)col;
      atomicMin(pKey + row, key);
    }
  }
}

// ---------------------------------------------------------------------------
// finalize: gather codes + write index as float.
// ---------------------------------------------------------------------------
__global__ __launch_bounds__(256) void final_kernel(const float* __restrict__ embed,
                                                    const unsigned long long* __restrict__ pKey,
                                                    float* __restrict__ outQ,
                                                    float* __restrict__ indF) {
  int wid  = threadIdx.x >> 6;
  int lane = threadIdx.x & 63;
  int row  = blockIdx.x * 4 + wid;
  unsigned long long k = pKey[row];
  int idx = (int)(k & 8191ull);
  float4 v = *(const float4*)&embed[(size_t)idx * D + lane * 4];
  *(float4*)&outQ[(size_t)row * D + lane * 4] = v;
  if (lane == 0) indF[row] = (float)idx;
}

// ===========================================================================
// Fallback fp32 path (round-1, proven) — used if ws_size < WS_NEED.
// ===========================================================================
#define BM_F 128
#define BN_F 128
#define BK_F 32
#define NSPLIT_F 4
#define SPLIT_CF (CODES / NSPLIT_F)

__global__ __launch_bounds__(256) void sq_kernel(const float* __restrict__ x,
                                                 const float* __restrict__ embed,
                                                 float* __restrict__ x2,
                                                 float* __restrict__ e2) {
  int wid  = threadIdx.x >> 6;
  int lane = threadIdx.x & 63;
  int rid  = blockIdx.x * 4 + wid;
  const float* base = (rid < NROWS) ? (x + (size_t)rid * D)
                                    : (embed + (size_t)(rid - NROWS) * D);
  float4 v = *(const float4*)(base + lane * 4);
  float p = v.x * v.x + v.y * v.y + v.z * v.z + v.w * v.w;
  #pragma unroll
  for (int off = 32; off > 0; off >>= 1) p += __shfl_down(p, off);
  if (lane == 0) {
    if (rid < NROWS) x2[rid] = p;
    else             e2[rid - NROWS] = p;
  }
}

__global__ __launch_bounds__(256) void argmin_f32_kernel(const float* __restrict__ x,
                                                         const float* __restrict__ embed,
                                                         const float* __restrict__ x2,
                                                         const float* __restrict__ e2,
                                                         float* __restrict__ pVal,
                                                         int* __restrict__ pIdx) {
  __shared__ float As[BK_F][BM_F];
  __shared__ float Bs[BK_F][BN_F];
  const int tid = threadIdx.x;
  const int ty = tid >> 4, tx = tid & 15;
  const int rowBase = blockIdx.x * BM_F;
  const int split = blockIdx.y;
  const int r0 = ty * 8, c0 = tx * 8;
  float bestV[8]; int bestI[8];
  #pragma unroll
  for (int i = 0; i < 8; i++) { bestV[i] = -INFINITY; bestI[i] = 0; }
  float x2r[8];
  #pragma unroll
  for (int i = 0; i < 8; i++) x2r[i] = x2[rowBase + r0 + i];
  for (int chunk = 0; chunk < SPLIT_CF / BN_F; ++chunk) {
    const int cBase = split * SPLIT_CF + chunk * BN_F;
    float acc[8][8];
    #pragma unroll
    for (int i = 0; i < 8; i++)
      #pragma unroll
      for (int j = 0; j < 8; j++) acc[i][j] = 0.0f;
    for (int kb = 0; kb < D / BK_F; ++kb) {
      #pragma unroll
      for (int i = 0; i < 4; i++) {
        int f4 = tid + i * 256;
        int rr = f4 >> 3, k4 = f4 & 7;
        float4 va = *(const float4*)&x[(size_t)(rowBase + rr) * D + kb * BK_F + k4 * 4];
        As[k4 * 4 + 0][rr] = va.x; As[k4 * 4 + 1][rr] = va.y;
        As[k4 * 4 + 2][rr] = va.z; As[k4 * 4 + 3][rr] = va.w;
        float4 vb = *(const float4*)&embed[(size_t)(cBase + rr) * D + kb * BK_F + k4 * 4];
        Bs[k4 * 4 + 0][rr] = vb.x; Bs[k4 * 4 + 1][rr] = vb.y;
        Bs[k4 * 4 + 2][rr] = vb.z; Bs[k4 * 4 + 3][rr] = vb.w;
      }
      __syncthreads();
      #pragma unroll 8
      for (int kk = 0; kk < BK_F; kk++) {
        float a[8], b[8];
        *(float4*)&a[0] = *(const float4*)&As[kk][r0];
        *(float4*)&a[4] = *(const float4*)&As[kk][r0 + 4];
        *(float4*)&b[0] = *(const float4*)&Bs[kk][c0];
        *(float4*)&b[4] = *(const float4*)&Bs[kk][c0 + 4];
        #pragma unroll
        for (int i = 0; i < 8; i++)
          #pragma unroll
          for (int j = 0; j < 8; j++)
            acc[i][j] = fmaf(a[i], b[j], acc[i][j]);
      }
      __syncthreads();
    }
    #pragma unroll
    for (int j = 0; j < 8; j++) {
      int c = cBase + c0 + j;
      float e2c = e2[c];
      #pragma unroll
      for (int i = 0; i < 8; i++) {
        float s  = __fadd_rn(x2r[i], e2c);
        float u  = __fmul_rn(2.0f, acc[i][j]);
        float d2 = fmaxf(__fsub_rn(s, u), 0.0f);
        float dist = -sqrtf(d2);
        if (dist > bestV[i]) { bestV[i] = dist; bestI[i] = c; }
      }
    }
  }
  __syncthreads();
  float* Vl = &As[0][0];
  int*   Il = (int*)&Bs[0][0];
  #pragma unroll
  for (int i = 0; i < 8; i++) {
    Vl[(ty * 16 + tx) * 8 + i] = bestV[i];
    Il[(ty * 16 + tx) * 8 + i] = bestI[i];
  }
  __syncthreads();
  if (tid < BM_F) {
    int rr = tid, tyr = rr >> 3, ii = rr & 7;
    float bv = -INFINITY; int bi = 0;
    #pragma unroll
    for (int t = 0; t < 16; t++) {
      float v = Vl[(tyr * 16 + t) * 8 + ii];
      int  iv = Il[(tyr * 16 + t) * 8 + ii];
      if (v > bv || (v == bv && iv < bi)) { bv = v; bi = iv; }
    }
    pVal[split * NROWS + rowBase + rr] = bv;
    pIdx[split * NROWS + rowBase + rr] = bi;
  }
}

__global__ __launch_bounds__(256) void merge_f32_kernel(const float* __restrict__ pVal,
                                                        const int* __restrict__ pIdx,
                                                        float* __restrict__ indF) {
  int row = blockIdx.x * 256 + threadIdx.x;
  if (row >= NROWS) return;
  float bv = -INFINITY; int bi = 0;
  #pragma unroll
  for (int s = 0; s < NSPLIT_F; s++) {
    float v = pVal[s * NROWS + row];
    int  iv = pIdx[s * NROWS + row];
    if (v > bv || (v == bv && iv < bi)) { bv = v; bi = iv; }
  }
  indF[row] = (float)bi;
}

__global__ __launch_bounds__(256) void gather_f32_kernel(const float* __restrict__ embed,
                                                         const float* __restrict__ indF,
                                                         float* __restrict__ outQ) {
  int wid = threadIdx.x >> 6, lane = threadIdx.x & 63;
  int row = blockIdx.x * 4 + wid;
  int idx = (int)indF[row];
  float4 v = *(const float4*)&embed[(size_t)idx * D + lane * 4];
  *(float4*)&outQ[(size_t)row * D + lane * 4] = v;
}

// ---------------------------------------------------------------------------
extern "C" void kernel_launch(void* const* d_in, const int* in_sizes, int n_in,
                              void* d_out, int out_size, void* d_ws, size_t ws_size,
                              hipStream_t stream) {
  const float* x     = (const float*)d_in[0];
  const float* embed = (const float*)d_in[1];
  float* o = (float*)d_out;

  if (ws_size >= WS_NEED) {
    char* w = (char*)d_ws;
    unsigned short* A_h = (unsigned short*)(w + OFF_AH);
    float* x2 = (float*)(w + OFF_X2);
    float* nx = (float*)(w + OFF_NX);
    float* e2 = (float*)(w + OFF_E2);
    unsigned* rowMinU = (unsigned*)(w + OFF_RM);
    unsigned long long* pKey = (unsigned long long*)(w + OFF_PK);
    unsigned* misc = (unsigned*)(w + OFF_MISC);
    unsigned* blkCnt = (unsigned*)(w + OFF_BCNT);
    unsigned* list2 = (unsigned*)(w + OFF_L2);
    uint2* cand = (uint2*)(w + OFF_CAND);

    unsigned short* E_h = (unsigned short*)o;      // 4MB scratch in quantize region
    float* indF = o + QOFF;

    init_kernel<<<128, 256, 0, stream>>>(misc, rowMinU, pKey);
    prep_kernel<<<(NROWS + CODES) / 4, 256, 0, stream>>>(x, embed, A_h, E_h, x2, nx, e2);
    normmax_kernel<<<32, 256, 0, stream>>>(nx, e2, misc);
    dim3 gridC(NROWS / BM, NSPL);
    gemm_coarse<<<gridC, 256, 0, stream>>>(A_h, E_h, e2, misc, rowMinU,
                                           cand, blkCnt, &misc[1]);
    filter_kernel<<<NBLK, 256, 0, stream>>>(cand, blkCnt, misc, rowMinU, nx, list2);
    refine_kernel<<<1024, 256, 0, stream>>>(x, embed, x2, e2, misc, list2, pKey);
    final_kernel<<<NROWS / 4, 256, 0, stream>>>(embed, pKey, o, indF);
  } else {
    // ---- fp32 fallback ----
    float* x2   = o;
    float* e2   = o + 32768;
    float* pVal = o + 65536;
    int*   pIdx = (int*)(o + 196608);
    float* indF = o + QOFF;
    sq_kernel<<<(NROWS + CODES) / 4, 256, 0, stream>>>(x, embed, x2, e2);
    dim3 gridB(NROWS / BM_F, NSPLIT_F);
    argmin_f32_kernel<<<gridB, 256, 0, stream>>>(x, embed, x2, e2, pVal, pIdx);
    merge_f32_kernel<<<NROWS / 256, 256, 0, stream>>>(pVal, pIdx, indF);
    gather_f32_kernel<<<NROWS / 4, 256, 0, stream>>>(embed, indF, o);
  }
}